// Round 4
// baseline (1180.460 us; speedup 1.0000x reference)
//
#include <hip/hip_runtime.h>
#include <cstdint>
#include <cstddef>

#define N_NODES 100000
#define N_EDGES 3200000
#define IN_FEAT 512
#define HIDDEN  256
#define N_CLASS 40

#define N_BUCKETS 196        // ceil(100000 / 512), bucket = row >> 9
#define SC_CHUNK 4096        // edges per binscatter block (256 thr x 16)
#define N_SC_BLOCKS 782      // ceil(3.2e6 / 4096)

#define S1_NCHUNKS 16
#define S1_CHUNK_ELEMS ((size_t)N_NODES * 16)   // elems per feature-chunk slice

// ---------------------------------------------------------------------------
// Workspace layout (bytes), 256B-aligned
//   support1 : N_NODES*HIDDEN bf16 (chunked [16][N][16]) = 51,200,000
//   h        : N_NODES*HIDDEN bf16  =  51,200,000
//   support2 : N_NODES*N_CLASS f32  =  16,000,000
//   w1t      : HIDDEN x IN_FEAT bf16 =    262,144
//   rptr     : (N_NODES+1) i32      ->     400,128
//   bcnt/bbase/bcur : ~196 i32 each ->       1,024 each
//   binned   : N_EDGES int2         =  25,600,000
//   sedge    : N_EDGES int2         =  25,600,000
// ---------------------------------------------------------------------------
#define OFF_SUPPORT1 ((size_t)0)
#define OFF_H        ((size_t)51200000)
#define OFF_SUPPORT2 ((size_t)102400000)
#define OFF_W1T      ((size_t)118400000)
#define OFF_RPTR     ((size_t)118662144)
#define OFF_BCNT     ((size_t)119062272)
#define OFF_BBASE    ((size_t)119063296)
#define OFF_BCUR     ((size_t)119064320)
#define OFF_BINNED   ((size_t)119065344)
#define OFF_SEDGE    ((size_t)144665344)

typedef __attribute__((ext_vector_type(8))) short short8x;
typedef __attribute__((ext_vector_type(4))) float f32x4;

static __device__ __forceinline__ unsigned short f2bf(float f) {
  unsigned u = __float_as_uint(f);
  unsigned r = (u + 0x7FFFu + ((u >> 16) & 1u)) >> 16;  // RNE
  return (unsigned short)r;
}
static __device__ __forceinline__ float bf2f(unsigned short s) {
  return __uint_as_float(((unsigned)s) << 16);
}

// ----------------------- bucketed CSR build --------------------------------
__global__ __launch_bounds__(256) void k_bincnt(const int* __restrict__ erow,
                                                int* __restrict__ bcnt) {
  __shared__ int lh[256];
  lh[threadIdx.x] = 0;
  __syncthreads();
  int i = blockIdx.x * blockDim.x + threadIdx.x;
  int stride = gridDim.x * blockDim.x;
  for (; i < N_EDGES; i += stride) atomicAdd(&lh[erow[i] >> 9], 1);
  __syncthreads();
  if (threadIdx.x < N_BUCKETS) atomicAdd(&bcnt[threadIdx.x], lh[threadIdx.x]);
}

__global__ __launch_bounds__(256) void k_binscan(const int* __restrict__ bcnt,
                                                 int* __restrict__ bbase,
                                                 int* __restrict__ bcur,
                                                 int* __restrict__ rptr) {
  __shared__ int s[256];
  int t = threadIdx.x;
  int v = (t < N_BUCKETS) ? bcnt[t] : 0;
  s[t] = v;
  __syncthreads();
  for (int off = 1; off < 256; off <<= 1) {
    int y = (t >= off) ? s[t - off] : 0;
    __syncthreads();
    s[t] += y;
    __syncthreads();
  }
  if (t < N_BUCKETS) {
    int e = s[t] - v;
    bbase[t] = e;
    bcur[t] = e;
  }
  if (t == 0) {
    bbase[N_BUCKETS] = N_EDGES;
    rptr[N_NODES] = N_EDGES;
  }
}

__global__ __launch_bounds__(256) void k_binscatter(const int* __restrict__ erow,
                                                    const int* __restrict__ ecol,
                                                    const float* __restrict__ eval,
                                                    int* __restrict__ bcur,
                                                    int2* __restrict__ binned) {
  __shared__ int lcnt[256];
  __shared__ int lcur[256];
  const int t = threadIdx.x;
  const int base = blockIdx.x * SC_CHUNK;
  lcnt[t] = 0;
  __syncthreads();
  int rows[16], cols[16], vals[16];
#pragma unroll
  for (int e = 0; e < 16; e++) {
    int i = base + t + e * 256;
    if (i < N_EDGES) {
      rows[e] = erow[i];
      cols[e] = ecol[i];
      vals[e] = __float_as_int(eval[i]);
      atomicAdd(&lcnt[rows[e] >> 9], 1);
    } else {
      rows[e] = -1;
    }
  }
  __syncthreads();
  if (t < N_BUCKETS) lcur[t] = atomicAdd(&bcur[t], lcnt[t]);
  __syncthreads();
#pragma unroll
  for (int e = 0; e < 16; e++) {
    if (rows[e] >= 0) {
      int bkt = rows[e] >> 9;
      int p = atomicAdd(&lcur[bkt], 1);
      binned[p] = make_int2(((rows[e] & 511) << 17) | cols[e], vals[e]);
    }
  }
}

__global__ __launch_bounds__(256) void k_bucket_csr(const int2* __restrict__ binned,
                                                    const int* __restrict__ bbase,
                                                    int* __restrict__ rptr,
                                                    int2* __restrict__ sedge) {
  const int b = blockIdx.x;
  const int t = threadIdx.x;
  __shared__ int cnt[512];
  __shared__ int excl[512];
  __shared__ int s[256];
  cnt[t] = 0;
  cnt[t + 256] = 0;
  __syncthreads();
  const int ebase = bbase[b];
  const int ecnt = bbase[b + 1] - ebase;
  for (int i = t; i < ecnt; i += 256)
    atomicAdd(&cnt[((unsigned)binned[ebase + i].x) >> 17], 1);
  __syncthreads();
  int c0 = cnt[2 * t], c1 = cnt[2 * t + 1];
  s[t] = c0 + c1;
  __syncthreads();
  for (int off = 1; off < 256; off <<= 1) {
    int y = (t >= off) ? s[t - off] : 0;
    __syncthreads();
    s[t] += y;
    __syncthreads();
  }
  int e = s[t] - (c0 + c1);
  excl[2 * t] = e;
  excl[2 * t + 1] = e + c0;
  __syncthreads();
  for (int i = t; i < 512; i += 256) {
    int node = b * 512 + i;
    if (node < N_NODES) rptr[node] = ebase + excl[i];
  }
  __syncthreads();
  for (int i = t; i < ecnt; i += 256) {
    int2 e2 = binned[ebase + i];
    int lrow = ((unsigned)e2.x) >> 17;
    int col = e2.x & 0x1FFFF;
    int p = atomicAdd(&excl[lrow], 1);
    sedge[ebase + p] = make_int2(col, e2.y);
  }
}

// ------------------- W1 (512x256 f32) -> W1t (256x512 bf16) -----------------
__global__ __launch_bounds__(256) void k_prep_w(const float* __restrict__ W,
                                                unsigned short* __restrict__ Wt) {
  int tid = blockIdx.x * 256 + threadIdx.x;  // 131072 total
  int n = tid & 255;
  int k = tid >> 8;
  Wt[(size_t)n * IN_FEAT + k] = f2bf(W[(size_t)k * HIDDEN + n]);
}

// ------------- GEMM1 (MFMA): support1 = bf16(X @ W1), chunked out -----------
// M=100000, N=256 (full width per block -> X read ONCE), K=512.
// 128x256 block tile, 4 waves each 64x128 (4x8 fragments), BK=32.
__global__ __launch_bounds__(256) void k_gemm1(const float* __restrict__ X,
                                               const unsigned short* __restrict__ Wt,
                                               unsigned short* __restrict__ C) {
  __shared__ short As[128 * 32];  // [m][k] 8 KB
  __shared__ short Bs[256 * 32];  // [n][k] 16 KB
  const int t = threadIdx.x;
  const int wave = t >> 6, lane = t & 63;
  const int q = lane >> 4, r = lane & 15;
  const int wm = (wave >> 1) * 64;   // 0 or 64
  const int wn = (wave & 1) * 128;   // 0 or 128
  const int m0 = blockIdx.x * 128;

  f32x4 acc[4][8];
#pragma unroll
  for (int mi = 0; mi < 4; mi++)
#pragma unroll
    for (int ni = 0; ni < 8; ni++) acc[mi][ni] = (f32x4){0.f, 0.f, 0.f, 0.f};

  for (int k0 = 0; k0 < IN_FEAT; k0 += 32) {
    // stage A: 128 rows x 32 k, fp32->bf16 (512 chunks of 8, 2/thread)
#pragma unroll
    for (int i = 0; i < 2; i++) {
      int cidx = t + i * 256;
      int row = cidx >> 2;
      int ko = (cidx & 3) * 8;
      int gr = m0 + row;
      if (gr > N_NODES - 1) gr = N_NODES - 1;
      const float4* src = (const float4*)&X[(size_t)gr * IN_FEAT + k0 + ko];
      float4 x0 = src[0], x1 = src[1];
      short8x a;
      a[0] = (short)f2bf(x0.x); a[1] = (short)f2bf(x0.y);
      a[2] = (short)f2bf(x0.z); a[3] = (short)f2bf(x0.w);
      a[4] = (short)f2bf(x1.x); a[5] = (short)f2bf(x1.y);
      a[6] = (short)f2bf(x1.z); a[7] = (short)f2bf(x1.w);
      *(short8x*)&As[row * 32 + ko] = a;
    }
    // stage B: 256 n-rows x 32 k (1024 chunks of 8, 4/thread)
#pragma unroll
    for (int i = 0; i < 4; i++) {
      int cidx = t + i * 256;
      int row = cidx >> 2;
      int ko = (cidx & 3) * 8;
      short8x b = *(const short8x*)&Wt[(size_t)row * IN_FEAT + k0 + ko];
      *(short8x*)&Bs[row * 32 + ko] = b;
    }
    __syncthreads();
    short8x af[4], bf[8];
#pragma unroll
    for (int mi = 0; mi < 4; mi++)
      af[mi] = *(const short8x*)&As[(wm + mi * 16 + r) * 32 + q * 8];
#pragma unroll
    for (int ni = 0; ni < 8; ni++)
      bf[ni] = *(const short8x*)&Bs[(wn + ni * 16 + r) * 32 + q * 8];
#pragma unroll
    for (int mi = 0; mi < 4; mi++)
#pragma unroll
      for (int ni = 0; ni < 8; ni++)
        acc[mi][ni] = __builtin_amdgcn_mfma_f32_16x16x32_bf16(af[mi], bf[ni],
                                                              acc[mi][ni], 0, 0, 0);
    __syncthreads();
  }
  // epilogue into chunked layout [chunk][node][16]; col&15 == r
#pragma unroll
  for (int mi = 0; mi < 4; mi++) {
#pragma unroll
    for (int ni = 0; ni < 8; ni++) {
      int chunk = (wn >> 4) + ni;
#pragma unroll
      for (int reg = 0; reg < 4; reg++) {
        int row = m0 + wm + mi * 16 + q * 4 + reg;
        if (row < N_NODES)
          C[(size_t)chunk * S1_CHUNK_ELEMS + (size_t)row * 16 + r] =
              f2bf(acc[mi][ni][reg]);
      }
    }
  }
}

// -------- SpMM1 (feature-chunked): h = bf16(relu(A @ support1 + b1)) --------
// grid = (N_NODES/4, 16 chunks). Wave = 1 node x 1 chunk (16 feats).
// Lane split: e8 = lane>>3 (8 edges in flight), f2 = lane&7 (ushort2 feats).
// Chunk slice = 3.2 MB -> resident in each XCD's 4 MB L2.
__global__ __launch_bounds__(256) void k_spmm1(const unsigned short* __restrict__ S,
                                               const int* __restrict__ rptr,
                                               const int2* __restrict__ sedge,
                                               const float* __restrict__ b1,
                                               unsigned short* __restrict__ H) {
  const int node = (blockIdx.x * blockDim.x + threadIdx.x) >> 6;
  const int chunk = blockIdx.y;
  const int lane = threadIdx.x & 63;
  const int e8 = lane >> 3;
  const int f2 = lane & 7;
  const unsigned short* Sc = S + (size_t)chunk * S1_CHUNK_ELEMS;
  int e0 = rptr[node], e1 = rptr[node + 1];
  float a0 = 0.f, a1 = 0.f;
  for (int base = e0; base < e1; base += 64) {
    int rem = e1 - base;
    int c = 0;
    float v = 0.f;
    if (lane < rem) {
      int2 e = sedge[base + lane];
      c = e.x;
      v = __int_as_float(e.y);
    }
#pragma unroll
    for (int j = 0; j < 8; j++) {
      int idx = j * 8 + e8;
      int cj = __shfl(c, idx);
      float vj = __shfl(v, idx);
      ushort2 s2 = *(const ushort2*)&Sc[(size_t)cj * 16 + f2 * 2];
      a0 += vj * bf2f(s2.x);
      a1 += vj * bf2f(s2.y);
    }
  }
#pragma unroll
  for (int off = 8; off < 64; off <<= 1) {
    a0 += __shfl_xor(a0, off);
    a1 += __shfl_xor(a1, off);
  }
  if (e8 == 0) {
    int fbase = chunk * 16 + f2 * 2;
    float2 bb = *(const float2*)&b1[fbase];
    ushort2 o;
    o.x = f2bf(fmaxf(a0 + bb.x, 0.f));
    o.y = f2bf(fmaxf(a1 + bb.y, 0.f));
    *(ushort2*)&H[(size_t)node * HIDDEN + fbase] = o;
  }
}

// --------------------- GEMM2: support2 = H @ W2 (H bf16) --------------------
__global__ __launch_bounds__(256) void k_gemm2(const unsigned short* __restrict__ H,
                                               const float* __restrict__ W2,
                                               float* __restrict__ S2) {
  __shared__ __align__(16) float Ws[HIDDEN][N_CLASS];  // 40 KB
  __shared__ float Hs[256][33];
  const int t = threadIdx.x;
  const int r0 = blockIdx.x * 256;

#pragma unroll
  for (int i = 0; i < 10; i++) {
    int qq = t + i * 256;
    float4 w = *(const float4*)&W2[(size_t)qq * 4];
    *(float4*)&((float*)Ws)[(size_t)qq * 4] = w;
  }

  float acc[N_CLASS];
#pragma unroll
  for (int n = 0; n < N_CLASS; n++) acc[n] = 0.f;

  for (int kc = 0; kc < HIDDEN; kc += 32) {
    __syncthreads();
#pragma unroll
    for (int i = 0; i < 8; i++) {
      int qq = t + i * 256;
      int row = qq >> 3;
      int kv = (qq & 7) * 4;
      int grow = r0 + row;
      if (grow > N_NODES - 1) grow = N_NODES - 1;
      ushort4 hv = *(const ushort4*)&H[(size_t)grow * HIDDEN + kc + kv];
      Hs[row][kv + 0] = bf2f(hv.x);
      Hs[row][kv + 1] = bf2f(hv.y);
      Hs[row][kv + 2] = bf2f(hv.z);
      Hs[row][kv + 3] = bf2f(hv.w);
    }
    __syncthreads();
    const float4* Wsv = (const float4*)Ws;
#pragma unroll
    for (int k = 0; k < 32; k++) {
      float hk = Hs[t][k];
      int kg = kc + k;
#pragma unroll
      for (int n4 = 0; n4 < 10; n4++) {
        float4 w = Wsv[kg * 10 + n4];
        acc[n4 * 4 + 0] += hk * w.x;
        acc[n4 * 4 + 1] += hk * w.y;
        acc[n4 * 4 + 2] += hk * w.z;
        acc[n4 * 4 + 3] += hk * w.w;
      }
    }
  }
  int row = r0 + t;
  if (row < N_NODES) {
#pragma unroll
    for (int n4 = 0; n4 < 10; n4++) {
      float4 o = {acc[n4 * 4 + 0], acc[n4 * 4 + 1], acc[n4 * 4 + 2], acc[n4 * 4 + 3]};
      *(float4*)&S2[(size_t)row * N_CLASS + n4 * 4] = o;
    }
  }
}

// --------- SpMM2 + bias + log_softmax -------------------------------------
__global__ __launch_bounds__(256) void k_spmm2(const float* __restrict__ S2,
                                               const int* __restrict__ rptr,
                                               const int2* __restrict__ sedge,
                                               const float* __restrict__ b2,
                                               float* __restrict__ out) {
  const int wid = (blockIdx.x * blockDim.x + threadIdx.x) >> 6;
  const int lane = threadIdx.x & 63;
  const bool act = lane < N_CLASS;
  const int f = act ? lane : 0;
  int e0 = rptr[wid], e1 = rptr[wid + 1];
  float acc = 0.f;
  for (int base = e0; base < e1; base += 64) {
    int rem = min(64, e1 - base);
    int c = 0;
    float v = 0.f;
    if (lane < rem) {
      int2 e = sedge[base + lane];
      c = e.x;
      v = __int_as_float(e.y);
    }
    for (int j = 0; j < rem; j++) {
      int cj = __shfl(c, j);
      float vj = __shfl(v, j);
      if (act) acc += vj * S2[(size_t)cj * N_CLASS + f];
    }
  }
  float x = act ? (acc + b2[f]) : -INFINITY;
  float m = x;
#pragma unroll
  for (int o = 32; o > 0; o >>= 1) m = fmaxf(m, __shfl_xor(m, o));
  float ex = act ? expf(x - m) : 0.f;
  float s = ex;
#pragma unroll
  for (int o = 32; o > 0; o >>= 1) s += __shfl_xor(s, o);
  if (act) out[(size_t)wid * N_CLASS + lane] = (x - m) - logf(s);
}

// ---------------------------------------------------------------------------
extern "C" void kernel_launch(void* const* d_in, const int* in_sizes, int n_in,
                              void* d_out, int out_size, void* d_ws, size_t ws_size,
                              hipStream_t stream) {
  const float* x    = (const float*)d_in[0];
  const float* w1   = (const float*)d_in[1];
  const float* b1   = (const float*)d_in[2];
  const float* w2   = (const float*)d_in[3];
  const float* b2   = (const float*)d_in[4];
  const float* eval = (const float*)d_in[5];
  const int*   erow = (const int*)d_in[6];
  const int*   ecol = (const int*)d_in[7];
  float* out = (float*)d_out;

  char* ws = (char*)d_ws;
  unsigned short* support1 = (unsigned short*)(ws + OFF_SUPPORT1);
  unsigned short* h        = (unsigned short*)(ws + OFF_H);
  float* support2 = (float*)(ws + OFF_SUPPORT2);
  unsigned short* w1t = (unsigned short*)(ws + OFF_W1T);
  int*   rptr   = (int*)(ws + OFF_RPTR);
  int*   bcnt   = (int*)(ws + OFF_BCNT);
  int*   bbase  = (int*)(ws + OFF_BBASE);
  int*   bcur   = (int*)(ws + OFF_BCUR);
  int2*  binned = (int2*)(ws + OFF_BINNED);
  int2*  sedge  = (int2*)(ws + OFF_SEDGE);

  // ---- CSR build (bucketed) + weight prep ----
  hipMemsetAsync(bcnt, 0, N_BUCKETS * 4, stream);
  k_prep_w<<<512, 256, 0, stream>>>(w1, w1t);
  k_bincnt<<<512, 256, 0, stream>>>(erow, bcnt);
  k_binscan<<<1, 256, 0, stream>>>(bcnt, bbase, bcur, rptr);
  k_binscatter<<<N_SC_BLOCKS, 256, 0, stream>>>(erow, ecol, eval, bcur, binned);
  k_bucket_csr<<<N_BUCKETS, 256, 0, stream>>>(binned, bbase, rptr, sedge);

  // ---- layer 1 ----
  k_gemm1<<<dim3((N_NODES + 127) / 128, 1), 256, 0, stream>>>(x, w1t, support1);
  k_spmm1<<<dim3(N_NODES / 4, S1_NCHUNKS), 256, 0, stream>>>(support1, rptr, sedge, b1, h);

  // ---- layer 2 ----
  k_gemm2<<<(N_NODES + 255) / 256, 256, 0, stream>>>(h, w2, support2);
  k_spmm2<<<N_NODES / 4, 256, 0, stream>>>(support2, rptr, sedge, b2, out);
}

// Round 5
// 988.276 us; speedup vs baseline: 1.1945x; 1.1945x over previous
//
#include <hip/hip_runtime.h>
#include <cstdint>
#include <cstddef>

#define N_NODES 100000
#define N_EDGES 3200000
#define IN_FEAT 512
#define HIDDEN  256
#define N_CLASS 40

#define N_BUCKETS 196        // ceil(100000 / 512), bucket = row >> 9
#define SC_CHUNK 4096        // edges per binscatter block (256 thr x 16)
#define N_SC_BLOCKS 782      // ceil(3.2e6 / 4096)

// ---------------------------------------------------------------------------
// Workspace layout (bytes), 256B-aligned
//   support1 : N_NODES*HIDDEN bf16 (row-major) = 51,200,000
//   h        : N_NODES*HIDDEN bf16  =  51,200,000
//   support2 : N_NODES*N_CLASS f32  =  16,000,000
//   w1t      : HIDDEN x IN_FEAT bf16 =    262,144
//   rptr     : (N_NODES+1) i32      ->     400,128
//   bcnt/bbase/bcur : ~196 i32 each ->       1,024 each
//   binned   : N_EDGES int2         =  25,600,000
//   sedge    : N_EDGES int2         =  25,600,000
// ---------------------------------------------------------------------------
#define OFF_SUPPORT1 ((size_t)0)
#define OFF_H        ((size_t)51200000)
#define OFF_SUPPORT2 ((size_t)102400000)
#define OFF_W1T      ((size_t)118400000)
#define OFF_RPTR     ((size_t)118662144)
#define OFF_BCNT     ((size_t)119062272)
#define OFF_BBASE    ((size_t)119063296)
#define OFF_BCUR     ((size_t)119064320)
#define OFF_BINNED   ((size_t)119065344)
#define OFF_SEDGE    ((size_t)144665344)

typedef __attribute__((ext_vector_type(8))) short short8x;
typedef __attribute__((ext_vector_type(4))) float f32x4;
typedef __attribute__((ext_vector_type(4))) float f4v;
typedef __attribute__((ext_vector_type(2))) int i2v;
typedef __attribute__((ext_vector_type(4))) unsigned short u16x4;

static __device__ __forceinline__ unsigned short f2bf(float f) {
  unsigned u = __float_as_uint(f);
  unsigned r = (u + 0x7FFFu + ((u >> 16) & 1u)) >> 16;  // RNE
  return (unsigned short)r;
}
static __device__ __forceinline__ float bf2f(unsigned short s) {
  return __uint_as_float(((unsigned)s) << 16);
}

// ----------------------- bucketed CSR build --------------------------------
__global__ __launch_bounds__(256) void k_bincnt(const int* __restrict__ erow,
                                                int* __restrict__ bcnt) {
  __shared__ int lh[256];
  lh[threadIdx.x] = 0;
  __syncthreads();
  int i = blockIdx.x * blockDim.x + threadIdx.x;
  int stride = gridDim.x * blockDim.x;
  for (; i < N_EDGES; i += stride) atomicAdd(&lh[erow[i] >> 9], 1);
  __syncthreads();
  if (threadIdx.x < N_BUCKETS) atomicAdd(&bcnt[threadIdx.x], lh[threadIdx.x]);
}

__global__ __launch_bounds__(256) void k_binscan(const int* __restrict__ bcnt,
                                                 int* __restrict__ bbase,
                                                 int* __restrict__ bcur,
                                                 int* __restrict__ rptr) {
  __shared__ int s[256];
  int t = threadIdx.x;
  int v = (t < N_BUCKETS) ? bcnt[t] : 0;
  s[t] = v;
  __syncthreads();
  for (int off = 1; off < 256; off <<= 1) {
    int y = (t >= off) ? s[t - off] : 0;
    __syncthreads();
    s[t] += y;
    __syncthreads();
  }
  if (t < N_BUCKETS) {
    int e = s[t] - v;
    bbase[t] = e;
    bcur[t] = e;
  }
  if (t == 0) {
    bbase[N_BUCKETS] = N_EDGES;
    rptr[N_NODES] = N_EDGES;
  }
}

__global__ __launch_bounds__(256) void k_binscatter(const int* __restrict__ erow,
                                                    const int* __restrict__ ecol,
                                                    const float* __restrict__ eval,
                                                    int* __restrict__ bcur,
                                                    int2* __restrict__ binned) {
  __shared__ int lcnt[256];
  __shared__ int lcur[256];
  const int t = threadIdx.x;
  const int base = blockIdx.x * SC_CHUNK;
  lcnt[t] = 0;
  __syncthreads();
  int rows[16], cols[16], vals[16];
#pragma unroll
  for (int e = 0; e < 16; e++) {
    int i = base + t + e * 256;
    if (i < N_EDGES) {
      rows[e] = erow[i];
      cols[e] = ecol[i];
      vals[e] = __float_as_int(eval[i]);
      atomicAdd(&lcnt[rows[e] >> 9], 1);
    } else {
      rows[e] = -1;
    }
  }
  __syncthreads();
  if (t < N_BUCKETS) lcur[t] = atomicAdd(&bcur[t], lcnt[t]);
  __syncthreads();
#pragma unroll
  for (int e = 0; e < 16; e++) {
    if (rows[e] >= 0) {
      int bkt = rows[e] >> 9;
      int p = atomicAdd(&lcur[bkt], 1);
      binned[p] = make_int2(((rows[e] & 511) << 17) | cols[e], vals[e]);
    }
  }
}

__global__ __launch_bounds__(256) void k_bucket_csr(const int2* __restrict__ binned,
                                                    const int* __restrict__ bbase,
                                                    int* __restrict__ rptr,
                                                    int2* __restrict__ sedge) {
  const int b = blockIdx.x;
  const int t = threadIdx.x;
  __shared__ int cnt[512];
  __shared__ int excl[512];
  __shared__ int s[256];
  cnt[t] = 0;
  cnt[t + 256] = 0;
  __syncthreads();
  const int ebase = bbase[b];
  const int ecnt = bbase[b + 1] - ebase;
  for (int i = t; i < ecnt; i += 256)
    atomicAdd(&cnt[((unsigned)binned[ebase + i].x) >> 17], 1);
  __syncthreads();
  int c0 = cnt[2 * t], c1 = cnt[2 * t + 1];
  s[t] = c0 + c1;
  __syncthreads();
  for (int off = 1; off < 256; off <<= 1) {
    int y = (t >= off) ? s[t - off] : 0;
    __syncthreads();
    s[t] += y;
    __syncthreads();
  }
  int e = s[t] - (c0 + c1);
  excl[2 * t] = e;
  excl[2 * t + 1] = e + c0;
  __syncthreads();
  for (int i = t; i < 512; i += 256) {
    int node = b * 512 + i;
    if (node < N_NODES) rptr[node] = ebase + excl[i];
  }
  __syncthreads();
  for (int i = t; i < ecnt; i += 256) {
    int2 e2 = binned[ebase + i];
    int lrow = ((unsigned)e2.x) >> 17;
    int col = e2.x & 0x1FFFF;
    int p = atomicAdd(&excl[lrow], 1);
    sedge[ebase + p] = make_int2(col, e2.y);
  }
}

// ------------------- W1 (512x256 f32) -> W1t (256x512 bf16) -----------------
__global__ __launch_bounds__(256) void k_prep_w(const float* __restrict__ W,
                                                unsigned short* __restrict__ Wt) {
  int tid = blockIdx.x * 256 + threadIdx.x;  // 131072 total
  int n = tid & 255;
  int k = tid >> 8;
  Wt[(size_t)n * IN_FEAT + k] = f2bf(W[(size_t)k * HIDDEN + n]);
}

// ------------- GEMM1 (MFMA): support1 = bf16(X @ W1), row-major out ---------
// M=100000, N=256 (full width per block -> X read ONCE), K=512.
// 128x256 block tile, 4 waves each 64x128 (4x8 fragments), BK=32.
// X loads are nontemporal: 205 MB stream must not evict support1 from L3.
__global__ __launch_bounds__(256) void k_gemm1(const float* __restrict__ X,
                                               const unsigned short* __restrict__ Wt,
                                               unsigned short* __restrict__ C) {
  __shared__ short As[128 * 32];  // [m][k] 8 KB
  __shared__ short Bs[256 * 32];  // [n][k] 16 KB
  const int t = threadIdx.x;
  const int wave = t >> 6, lane = t & 63;
  const int q = lane >> 4, r = lane & 15;
  const int wm = (wave >> 1) * 64;   // 0 or 64
  const int wn = (wave & 1) * 128;   // 0 or 128
  const int m0 = blockIdx.x * 128;

  f32x4 acc[4][8];
#pragma unroll
  for (int mi = 0; mi < 4; mi++)
#pragma unroll
    for (int ni = 0; ni < 8; ni++) acc[mi][ni] = (f32x4){0.f, 0.f, 0.f, 0.f};

  for (int k0 = 0; k0 < IN_FEAT; k0 += 32) {
    // stage A: 128 rows x 32 k, fp32->bf16 (512 chunks of 8, 2/thread)
#pragma unroll
    for (int i = 0; i < 2; i++) {
      int cidx = t + i * 256;
      int row = cidx >> 2;
      int ko = (cidx & 3) * 8;
      int gr = m0 + row;
      if (gr > N_NODES - 1) gr = N_NODES - 1;
      const f4v* src = (const f4v*)&X[(size_t)gr * IN_FEAT + k0 + ko];
      f4v x0 = __builtin_nontemporal_load(src);
      f4v x1 = __builtin_nontemporal_load(src + 1);
      short8x a;
      a[0] = (short)f2bf(x0.x); a[1] = (short)f2bf(x0.y);
      a[2] = (short)f2bf(x0.z); a[3] = (short)f2bf(x0.w);
      a[4] = (short)f2bf(x1.x); a[5] = (short)f2bf(x1.y);
      a[6] = (short)f2bf(x1.z); a[7] = (short)f2bf(x1.w);
      *(short8x*)&As[row * 32 + ko] = a;
    }
    // stage B: 256 n-rows x 32 k (1024 chunks of 8, 4/thread)
#pragma unroll
    for (int i = 0; i < 4; i++) {
      int cidx = t + i * 256;
      int row = cidx >> 2;
      int ko = (cidx & 3) * 8;
      short8x b = *(const short8x*)&Wt[(size_t)row * IN_FEAT + k0 + ko];
      *(short8x*)&Bs[row * 32 + ko] = b;
    }
    __syncthreads();
    short8x af[4], bf[8];
#pragma unroll
    for (int mi = 0; mi < 4; mi++)
      af[mi] = *(const short8x*)&As[(wm + mi * 16 + r) * 32 + q * 8];
#pragma unroll
    for (int ni = 0; ni < 8; ni++)
      bf[ni] = *(const short8x*)&Bs[(wn + ni * 16 + r) * 32 + q * 8];
#pragma unroll
    for (int mi = 0; mi < 4; mi++)
#pragma unroll
      for (int ni = 0; ni < 8; ni++)
        acc[mi][ni] = __builtin_amdgcn_mfma_f32_16x16x32_bf16(af[mi], bf[ni],
                                                              acc[mi][ni], 0, 0, 0);
    __syncthreads();
  }
  // epilogue, row-major: C/D layout col=lane&15, row=(lane>>4)*4+reg
#pragma unroll
  for (int mi = 0; mi < 4; mi++) {
#pragma unroll
    for (int ni = 0; ni < 8; ni++) {
      int col = wn + ni * 16 + r;
#pragma unroll
      for (int reg = 0; reg < 4; reg++) {
        int row = m0 + wm + mi * 16 + q * 4 + reg;
        if (row < N_NODES)
          C[(size_t)row * HIDDEN + col] = f2bf(acc[mi][ni][reg]);
      }
    }
  }
}

// ---------------- SpMM1: h = bf16(relu(A @ support1 + b1)) ------------------
// one wave per node; lane handles 4 features via ushort4 (bf16x4) loads.
// sedge read nontemporal (single use); H store nontemporal (single producer);
// S gathers cached (51.2 MB table, want it L3-resident).
__global__ __launch_bounds__(256) void k_spmm1(const unsigned short* __restrict__ S,
                                               const int* __restrict__ rptr,
                                               const int2* __restrict__ sedge,
                                               const float* __restrict__ b1,
                                               unsigned short* __restrict__ H) {
  const int wid = (blockIdx.x * blockDim.x + threadIdx.x) >> 6;  // node
  const int lane = threadIdx.x & 63;
  int e0 = rptr[wid], e1 = rptr[wid + 1];
  float a0 = 0.f, a1 = 0.f, a2 = 0.f, a3 = 0.f;
  for (int base = e0; base < e1; base += 64) {
    int rem = min(64, e1 - base);
    int c = 0;
    float v = 0.f;
    if (lane < rem) {
      i2v e = __builtin_nontemporal_load((const i2v*)&sedge[base + lane]);
      c = e.x;
      v = __int_as_float(e.y);
    }
    for (int j = 0; j < rem; j++) {
      int cj = __shfl(c, j);
      float vj = __shfl(v, j);
      ushort4 s4 = *(const ushort4*)&S[(size_t)cj * HIDDEN + lane * 4];
      a0 += vj * bf2f(s4.x);
      a1 += vj * bf2f(s4.y);
      a2 += vj * bf2f(s4.z);
      a3 += vj * bf2f(s4.w);
    }
  }
  const float4 bb = *(const float4*)&b1[lane * 4];
  u16x4 o;
  o.x = f2bf(fmaxf(a0 + bb.x, 0.f));
  o.y = f2bf(fmaxf(a1 + bb.y, 0.f));
  o.z = f2bf(fmaxf(a2 + bb.z, 0.f));
  o.w = f2bf(fmaxf(a3 + bb.w, 0.f));
  __builtin_nontemporal_store(o, (u16x4*)&H[(size_t)wid * HIDDEN + lane * 4]);
}

// --------------------- GEMM2: support2 = H @ W2 (H bf16) --------------------
__global__ __launch_bounds__(256) void k_gemm2(const unsigned short* __restrict__ H,
                                               const float* __restrict__ W2,
                                               float* __restrict__ S2) {
  __shared__ __align__(16) float Ws[HIDDEN][N_CLASS];  // 40 KB
  __shared__ float Hs[256][33];
  const int t = threadIdx.x;
  const int r0 = blockIdx.x * 256;

#pragma unroll
  for (int i = 0; i < 10; i++) {
    int qq = t + i * 256;
    float4 w = *(const float4*)&W2[(size_t)qq * 4];
    *(float4*)&((float*)Ws)[(size_t)qq * 4] = w;
  }

  float acc[N_CLASS];
#pragma unroll
  for (int n = 0; n < N_CLASS; n++) acc[n] = 0.f;

  for (int kc = 0; kc < HIDDEN; kc += 32) {
    __syncthreads();
#pragma unroll
    for (int i = 0; i < 8; i++) {
      int qq = t + i * 256;
      int row = qq >> 3;
      int kv = (qq & 7) * 4;
      int grow = r0 + row;
      if (grow > N_NODES - 1) grow = N_NODES - 1;
      ushort4 hv = *(const ushort4*)&H[(size_t)grow * HIDDEN + kc + kv];
      Hs[row][kv + 0] = bf2f(hv.x);
      Hs[row][kv + 1] = bf2f(hv.y);
      Hs[row][kv + 2] = bf2f(hv.z);
      Hs[row][kv + 3] = bf2f(hv.w);
    }
    __syncthreads();
    const float4* Wsv = (const float4*)Ws;
#pragma unroll
    for (int k = 0; k < 32; k++) {
      float hk = Hs[t][k];
      int kg = kc + k;
#pragma unroll
      for (int n4 = 0; n4 < 10; n4++) {
        float4 w = Wsv[kg * 10 + n4];
        acc[n4 * 4 + 0] += hk * w.x;
        acc[n4 * 4 + 1] += hk * w.y;
        acc[n4 * 4 + 2] += hk * w.z;
        acc[n4 * 4 + 3] += hk * w.w;
      }
    }
  }
  int row = r0 + t;
  if (row < N_NODES) {
#pragma unroll
    for (int n4 = 0; n4 < 10; n4++) {
      float4 o = {acc[n4 * 4 + 0], acc[n4 * 4 + 1], acc[n4 * 4 + 2], acc[n4 * 4 + 3]};
      *(float4*)&S2[(size_t)row * N_CLASS + n4 * 4] = o;
    }
  }
}

// --------- SpMM2 + bias + log_softmax -------------------------------------
__global__ __launch_bounds__(256) void k_spmm2(const float* __restrict__ S2,
                                               const int* __restrict__ rptr,
                                               const int2* __restrict__ sedge,
                                               const float* __restrict__ b2,
                                               float* __restrict__ out) {
  const int wid = (blockIdx.x * blockDim.x + threadIdx.x) >> 6;
  const int lane = threadIdx.x & 63;
  const bool act = lane < N_CLASS;
  const int f = act ? lane : 0;
  int e0 = rptr[wid], e1 = rptr[wid + 1];
  float acc = 0.f;
  for (int base = e0; base < e1; base += 64) {
    int rem = min(64, e1 - base);
    int c = 0;
    float v = 0.f;
    if (lane < rem) {
      i2v e = __builtin_nontemporal_load((const i2v*)&sedge[base + lane]);
      c = e.x;
      v = __int_as_float(e.y);
    }
    for (int j = 0; j < rem; j++) {
      int cj = __shfl(c, j);
      float vj = __shfl(v, j);
      if (act) acc += vj * S2[(size_t)cj * N_CLASS + f];
    }
  }
  float x = act ? (acc + b2[f]) : -INFINITY;
  float m = x;
#pragma unroll
  for (int o = 32; o > 0; o >>= 1) m = fmaxf(m, __shfl_xor(m, o));
  float ex = act ? expf(x - m) : 0.f;
  float s = ex;
#pragma unroll
  for (int o = 32; o > 0; o >>= 1) s += __shfl_xor(s, o);
  if (act) out[(size_t)wid * N_CLASS + lane] = (x - m) - logf(s);
}

// ---------------------------------------------------------------------------
extern "C" void kernel_launch(void* const* d_in, const int* in_sizes, int n_in,
                              void* d_out, int out_size, void* d_ws, size_t ws_size,
                              hipStream_t stream) {
  const float* x    = (const float*)d_in[0];
  const float* w1   = (const float*)d_in[1];
  const float* b1   = (const float*)d_in[2];
  const float* w2   = (const float*)d_in[3];
  const float* b2   = (const float*)d_in[4];
  const float* eval = (const float*)d_in[5];
  const int*   erow = (const int*)d_in[6];
  const int*   ecol = (const int*)d_in[7];
  float* out = (float*)d_out;

  char* ws = (char*)d_ws;
  unsigned short* support1 = (unsigned short*)(ws + OFF_SUPPORT1);
  unsigned short* h        = (unsigned short*)(ws + OFF_H);
  float* support2 = (float*)(ws + OFF_SUPPORT2);
  unsigned short* w1t = (unsigned short*)(ws + OFF_W1T);
  int*   rptr   = (int*)(ws + OFF_RPTR);
  int*   bcnt   = (int*)(ws + OFF_BCNT);
  int*   bbase  = (int*)(ws + OFF_BBASE);
  int*   bcur   = (int*)(ws + OFF_BCUR);
  int2*  binned = (int2*)(ws + OFF_BINNED);
  int2*  sedge  = (int2*)(ws + OFF_SEDGE);

  // ---- CSR build (bucketed) + weight prep ----
  hipMemsetAsync(bcnt, 0, N_BUCKETS * 4, stream);
  k_prep_w<<<512, 256, 0, stream>>>(w1, w1t);
  k_bincnt<<<512, 256, 0, stream>>>(erow, bcnt);
  k_binscan<<<1, 256, 0, stream>>>(bcnt, bbase, bcur, rptr);
  k_binscatter<<<N_SC_BLOCKS, 256, 0, stream>>>(erow, ecol, eval, bcur, binned);
  k_bucket_csr<<<N_BUCKETS, 256, 0, stream>>>(binned, bbase, rptr, sedge);

  // ---- layer 1 ----
  k_gemm1<<<dim3((N_NODES + 127) / 128, 1), 256, 0, stream>>>(x, w1t, support1);
  k_spmm1<<<N_NODES / 4, 256, 0, stream>>>(support1, rptr, sedge, b1, h);

  // ---- layer 2 ----
  k_gemm2<<<(N_NODES + 255) / 256, 256, 0, stream>>>(h, w2, support2);
  k_spmm2<<<N_NODES / 4, 256, 0, stream>>>(support2, rptr, sedge, b2, out);
}

// Round 6
// 863.573 us; speedup vs baseline: 1.3669x; 1.1444x over previous
//
#include <hip/hip_runtime.h>
#include <cstdint>
#include <cstddef>

#define N_NODES 100000
#define N_EDGES 3200000
#define IN_FEAT 512
#define HIDDEN  256
#define N_CLASS 40
#define S2_STRIDE 48         // support2 rows padded 40 -> 48 fp32 (192 B)

#define N_BUCKETS 196        // ceil(100000 / 512), bucket = row >> 9
#define SC_CHUNK 4096        // edges per binscatter block (256 thr x 16)
#define N_SC_BLOCKS 782      // ceil(3.2e6 / 4096)

// ---------------------------------------------------------------------------
// Workspace layout (bytes), 256B-aligned
//   support1 : N_NODES*HIDDEN bf16 (row-major) = 51,200,000
//   h        : N_NODES*HIDDEN bf16  =  51,200,000
//   support2 : N_NODES*48 f32       =  19,200,000
//   w1t      : HIDDEN x IN_FEAT bf16 =    262,144
//   rptr     : (N_NODES+1) i32      ->     400,128
//   bcnt/bbase/bcur : ~196 i32 each ->       1,024 each
//   binned   : N_EDGES int2         =  25,600,000
//   sedge    : N_EDGES int2         =  25,600,000
// total ~173.5 MB
// ---------------------------------------------------------------------------
#define OFF_SUPPORT1 ((size_t)0)
#define OFF_H        ((size_t)51200000)
#define OFF_SUPPORT2 ((size_t)102400000)
#define OFF_W1T      ((size_t)121600000)
#define OFF_RPTR     ((size_t)121862144)
#define OFF_BCNT     ((size_t)122262272)
#define OFF_BBASE    ((size_t)122263296)
#define OFF_BCUR     ((size_t)122264320)
#define OFF_BINNED   ((size_t)122265344)
#define OFF_SEDGE    ((size_t)147865344)

typedef __attribute__((ext_vector_type(8))) short short8x;
typedef __attribute__((ext_vector_type(4))) float f32x4;
typedef __attribute__((ext_vector_type(8))) unsigned short u16x8;

static __device__ __forceinline__ unsigned short f2bf(float f) {
  unsigned u = __float_as_uint(f);
  unsigned r = (u + 0x7FFFu + ((u >> 16) & 1u)) >> 16;  // RNE
  return (unsigned short)r;
}
static __device__ __forceinline__ float bf2f(unsigned short s) {
  return __uint_as_float(((unsigned)s) << 16);
}

// ----------------------- bucketed CSR build --------------------------------
__global__ __launch_bounds__(256) void k_bincnt(const int* __restrict__ erow,
                                                int* __restrict__ bcnt) {
  __shared__ int lh[256];
  lh[threadIdx.x] = 0;
  __syncthreads();
  int i = blockIdx.x * blockDim.x + threadIdx.x;
  int stride = gridDim.x * blockDim.x;
  for (; i < N_EDGES; i += stride) atomicAdd(&lh[erow[i] >> 9], 1);
  __syncthreads();
  if (threadIdx.x < N_BUCKETS) atomicAdd(&bcnt[threadIdx.x], lh[threadIdx.x]);
}

__global__ __launch_bounds__(256) void k_binscan(const int* __restrict__ bcnt,
                                                 int* __restrict__ bbase,
                                                 int* __restrict__ bcur,
                                                 int* __restrict__ rptr) {
  __shared__ int s[256];
  int t = threadIdx.x;
  int v = (t < N_BUCKETS) ? bcnt[t] : 0;
  s[t] = v;
  __syncthreads();
  for (int off = 1; off < 256; off <<= 1) {
    int y = (t >= off) ? s[t - off] : 0;
    __syncthreads();
    s[t] += y;
    __syncthreads();
  }
  if (t < N_BUCKETS) {
    int e = s[t] - v;
    bbase[t] = e;
    bcur[t] = e;
  }
  if (t == 0) {
    bbase[N_BUCKETS] = N_EDGES;
    rptr[N_NODES] = N_EDGES;
  }
}

__global__ __launch_bounds__(256) void k_binscatter(const int* __restrict__ erow,
                                                    const int* __restrict__ ecol,
                                                    const float* __restrict__ eval,
                                                    int* __restrict__ bcur,
                                                    int2* __restrict__ binned) {
  __shared__ int lcnt[256];
  __shared__ int lcur[256];
  const int t = threadIdx.x;
  const int base = blockIdx.x * SC_CHUNK;
  lcnt[t] = 0;
  __syncthreads();
  int rows[16], cols[16], vals[16];
#pragma unroll
  for (int e = 0; e < 16; e++) {
    int i = base + t + e * 256;
    if (i < N_EDGES) {
      rows[e] = erow[i];
      cols[e] = ecol[i];
      vals[e] = __float_as_int(eval[i]);
      atomicAdd(&lcnt[rows[e] >> 9], 1);
    } else {
      rows[e] = -1;
    }
  }
  __syncthreads();
  if (t < N_BUCKETS) lcur[t] = atomicAdd(&bcur[t], lcnt[t]);
  __syncthreads();
#pragma unroll
  for (int e = 0; e < 16; e++) {
    if (rows[e] >= 0) {
      int bkt = rows[e] >> 9;
      int p = atomicAdd(&lcur[bkt], 1);
      binned[p] = make_int2(((rows[e] & 511) << 17) | cols[e], vals[e]);
    }
  }
}

__global__ __launch_bounds__(256) void k_bucket_csr(const int2* __restrict__ binned,
                                                    const int* __restrict__ bbase,
                                                    int* __restrict__ rptr,
                                                    int2* __restrict__ sedge) {
  const int b = blockIdx.x;
  const int t = threadIdx.x;
  __shared__ int cnt[512];
  __shared__ int excl[512];
  __shared__ int s[256];
  cnt[t] = 0;
  cnt[t + 256] = 0;
  __syncthreads();
  const int ebase = bbase[b];
  const int ecnt = bbase[b + 1] - ebase;
  for (int i = t; i < ecnt; i += 256)
    atomicAdd(&cnt[((unsigned)binned[ebase + i].x) >> 17], 1);
  __syncthreads();
  int c0 = cnt[2 * t], c1 = cnt[2 * t + 1];
  s[t] = c0 + c1;
  __syncthreads();
  for (int off = 1; off < 256; off <<= 1) {
    int y = (t >= off) ? s[t - off] : 0;
    __syncthreads();
    s[t] += y;
    __syncthreads();
  }
  int e = s[t] - (c0 + c1);
  excl[2 * t] = e;
  excl[2 * t + 1] = e + c0;
  __syncthreads();
  for (int i = t; i < 512; i += 256) {
    int node = b * 512 + i;
    if (node < N_NODES) rptr[node] = ebase + excl[i];
  }
  __syncthreads();
  for (int i = t; i < ecnt; i += 256) {
    int2 e2 = binned[ebase + i];
    int lrow = ((unsigned)e2.x) >> 17;
    int col = e2.x & 0x1FFFF;
    int p = atomicAdd(&excl[lrow], 1);
    sedge[ebase + p] = make_int2(col, e2.y);
  }
}

// ------------------- W1 (512x256 f32) -> W1t (256x512 bf16) -----------------
__global__ __launch_bounds__(256) void k_prep_w(const float* __restrict__ W,
                                                unsigned short* __restrict__ Wt) {
  int tid = blockIdx.x * 256 + threadIdx.x;  // 131072 total
  int n = tid & 255;
  int k = tid >> 8;
  Wt[(size_t)n * IN_FEAT + k] = f2bf(W[(size_t)k * HIDDEN + n]);
}

// ------------- GEMM1 (MFMA): support1 = bf16(X @ W1), row-major out ---------
// M=100000, N=256 (full width per block -> X read ONCE), K=512.
// 128x256 block tile, 4 waves each 64x128 (4x8 fragments), BK=32.
__global__ __launch_bounds__(256) void k_gemm1(const float* __restrict__ X,
                                               const unsigned short* __restrict__ Wt,
                                               unsigned short* __restrict__ C) {
  __shared__ short As[128 * 32];  // [m][k] 8 KB
  __shared__ short Bs[256 * 32];  // [n][k] 16 KB
  const int t = threadIdx.x;
  const int wave = t >> 6, lane = t & 63;
  const int q = lane >> 4, r = lane & 15;
  const int wm = (wave >> 1) * 64;   // 0 or 64
  const int wn = (wave & 1) * 128;   // 0 or 128
  const int m0 = blockIdx.x * 128;

  f32x4 acc[4][8];
#pragma unroll
  for (int mi = 0; mi < 4; mi++)
#pragma unroll
    for (int ni = 0; ni < 8; ni++) acc[mi][ni] = (f32x4){0.f, 0.f, 0.f, 0.f};

  for (int k0 = 0; k0 < IN_FEAT; k0 += 32) {
    // stage A: 128 rows x 32 k, fp32->bf16 (512 chunks of 8, 2/thread)
#pragma unroll
    for (int i = 0; i < 2; i++) {
      int cidx = t + i * 256;
      int row = cidx >> 2;
      int ko = (cidx & 3) * 8;
      int gr = m0 + row;
      if (gr > N_NODES - 1) gr = N_NODES - 1;
      const float4* src = (const float4*)&X[(size_t)gr * IN_FEAT + k0 + ko];
      float4 x0 = src[0], x1 = src[1];
      short8x a;
      a[0] = (short)f2bf(x0.x); a[1] = (short)f2bf(x0.y);
      a[2] = (short)f2bf(x0.z); a[3] = (short)f2bf(x0.w);
      a[4] = (short)f2bf(x1.x); a[5] = (short)f2bf(x1.y);
      a[6] = (short)f2bf(x1.z); a[7] = (short)f2bf(x1.w);
      *(short8x*)&As[row * 32 + ko] = a;
    }
    // stage B: 256 n-rows x 32 k (1024 chunks of 8, 4/thread)
#pragma unroll
    for (int i = 0; i < 4; i++) {
      int cidx = t + i * 256;
      int row = cidx >> 2;
      int ko = (cidx & 3) * 8;
      short8x b = *(const short8x*)&Wt[(size_t)row * IN_FEAT + k0 + ko];
      *(short8x*)&Bs[row * 32 + ko] = b;
    }
    __syncthreads();
    short8x af[4], bf[8];
#pragma unroll
    for (int mi = 0; mi < 4; mi++)
      af[mi] = *(const short8x*)&As[(wm + mi * 16 + r) * 32 + q * 8];
#pragma unroll
    for (int ni = 0; ni < 8; ni++)
      bf[ni] = *(const short8x*)&Bs[(wn + ni * 16 + r) * 32 + q * 8];
#pragma unroll
    for (int mi = 0; mi < 4; mi++)
#pragma unroll
      for (int ni = 0; ni < 8; ni++)
        acc[mi][ni] = __builtin_amdgcn_mfma_f32_16x16x32_bf16(af[mi], bf[ni],
                                                              acc[mi][ni], 0, 0, 0);
    __syncthreads();
  }
  // epilogue, row-major: C/D layout col=lane&15, row=(lane>>4)*4+reg
#pragma unroll
  for (int mi = 0; mi < 4; mi++) {
#pragma unroll
    for (int ni = 0; ni < 8; ni++) {
      int col = wn + ni * 16 + r;
#pragma unroll
      for (int reg = 0; reg < 4; reg++) {
        int row = m0 + wm + mi * 16 + q * 4 + reg;
        if (row < N_NODES)
          C[(size_t)row * HIDDEN + col] = f2bf(acc[mi][ni][reg]);
      }
    }
  }
}

// ---------------- SpMM1: h = bf16(relu(A @ support1 + b1)) ------------------
// one wave per node; 2 edge-slots x 32 lanes x ushort8 (16 B) per row.
// halves j-iterations vs 1-edge/iter; unroll 4 raises loads-in-flight.
__global__ __launch_bounds__(256) void k_spmm1(const unsigned short* __restrict__ S,
                                               const int* __restrict__ rptr,
                                               const int2* __restrict__ sedge,
                                               const float* __restrict__ b1,
                                               unsigned short* __restrict__ H) {
  const int node = (blockIdx.x * blockDim.x + threadIdx.x) >> 6;
  const int lane = threadIdx.x & 63;
  const int half = lane >> 5;   // edge slot 0/1
  const int fl = lane & 31;     // feature group: feats fl*8 .. fl*8+7
  int e0 = rptr[node], e1 = rptr[node + 1];
  float a[8];
#pragma unroll
  for (int k = 0; k < 8; k++) a[k] = 0.f;
  for (int base = e0; base < e1; base += 64) {
    int rem = min(64, e1 - base);
    int c = 0;
    float v = 0.f;
    if (lane < rem) {
      int2 e = sedge[base + lane];
      c = e.x;
      v = __int_as_float(e.y);
    }
    int iters = (rem + 1) >> 1;
#pragma unroll 4
    for (int j = 0; j < iters; j++) {
      int idx = 2 * j + half;            // inactive tail: c=0,v=0 -> adds 0
      int cj = __shfl(c, idx);
      float vj = __shfl(v, idx);
      short8x s8 = *(const short8x*)&S[(size_t)cj * HIDDEN + fl * 8];
#pragma unroll
      for (int k = 0; k < 8; k++)
        a[k] += vj * bf2f((unsigned short)s8[k]);
    }
  }
#pragma unroll
  for (int k = 0; k < 8; k++) a[k] += __shfl_xor(a[k], 32);
  if (half == 0) {
    float4 b0 = *(const float4*)&b1[fl * 8];
    float4 b4 = *(const float4*)&b1[fl * 8 + 4];
    u16x8 o;
    o[0] = f2bf(fmaxf(a[0] + b0.x, 0.f));
    o[1] = f2bf(fmaxf(a[1] + b0.y, 0.f));
    o[2] = f2bf(fmaxf(a[2] + b0.z, 0.f));
    o[3] = f2bf(fmaxf(a[3] + b0.w, 0.f));
    o[4] = f2bf(fmaxf(a[4] + b4.x, 0.f));
    o[5] = f2bf(fmaxf(a[5] + b4.y, 0.f));
    o[6] = f2bf(fmaxf(a[6] + b4.z, 0.f));
    o[7] = f2bf(fmaxf(a[7] + b4.w, 0.f));
    *(u16x8*)&H[(size_t)node * HIDDEN + fl * 8] = o;
  }
}

// ------------- GEMM2: support2 = H @ W2 (H bf16), 48-padded rows ------------
__global__ __launch_bounds__(256) void k_gemm2(const unsigned short* __restrict__ H,
                                               const float* __restrict__ W2,
                                               float* __restrict__ S2) {
  __shared__ __align__(16) float Ws[HIDDEN][N_CLASS];  // 40 KB
  __shared__ float Hs[256][33];
  const int t = threadIdx.x;
  const int r0 = blockIdx.x * 256;

#pragma unroll
  for (int i = 0; i < 10; i++) {
    int qq = t + i * 256;
    float4 w = *(const float4*)&W2[(size_t)qq * 4];
    *(float4*)&((float*)Ws)[(size_t)qq * 4] = w;
  }

  float acc[N_CLASS];
#pragma unroll
  for (int n = 0; n < N_CLASS; n++) acc[n] = 0.f;

  for (int kc = 0; kc < HIDDEN; kc += 32) {
    __syncthreads();
#pragma unroll
    for (int i = 0; i < 8; i++) {
      int qq = t + i * 256;
      int row = qq >> 3;
      int kv = (qq & 7) * 4;
      int grow = r0 + row;
      if (grow > N_NODES - 1) grow = N_NODES - 1;
      ushort4 hv = *(const ushort4*)&H[(size_t)grow * HIDDEN + kc + kv];
      Hs[row][kv + 0] = bf2f(hv.x);
      Hs[row][kv + 1] = bf2f(hv.y);
      Hs[row][kv + 2] = bf2f(hv.z);
      Hs[row][kv + 3] = bf2f(hv.w);
    }
    __syncthreads();
    const float4* Wsv = (const float4*)Ws;
#pragma unroll
    for (int k = 0; k < 32; k++) {
      float hk = Hs[t][k];
      int kg = kc + k;
#pragma unroll
      for (int n4 = 0; n4 < 10; n4++) {
        float4 w = Wsv[kg * 10 + n4];
        acc[n4 * 4 + 0] += hk * w.x;
        acc[n4 * 4 + 1] += hk * w.y;
        acc[n4 * 4 + 2] += hk * w.z;
        acc[n4 * 4 + 3] += hk * w.w;
      }
    }
  }
  int row = r0 + t;
  if (row < N_NODES) {
#pragma unroll
    for (int n4 = 0; n4 < 10; n4++) {
      float4 o = {acc[n4 * 4 + 0], acc[n4 * 4 + 1], acc[n4 * 4 + 2], acc[n4 * 4 + 3]};
      *(float4*)&S2[(size_t)row * S2_STRIDE + n4 * 4] = o;
    }
    float4 z = {0.f, 0.f, 0.f, 0.f};
    *(float4*)&S2[(size_t)row * S2_STRIDE + 40] = z;   // zero the pad
    *(float4*)&S2[(size_t)row * S2_STRIDE + 44] = z;
  }
}

// --------- SpMM2 + bias + log_softmax: 4 edge-slots x 16 lanes x float3 -----
__global__ __launch_bounds__(256) void k_spmm2(const float* __restrict__ S2,
                                               const int* __restrict__ rptr,
                                               const int2* __restrict__ sedge,
                                               const float* __restrict__ b2,
                                               float* __restrict__ out) {
  const int node = (blockIdx.x * blockDim.x + threadIdx.x) >> 6;
  const int lane = threadIdx.x & 63;
  const int q = lane >> 4;    // edge slot 0..3
  const int fl = lane & 15;   // feats fl*3 .. fl*3+2 (covers 0..47 incl pad)
  int e0 = rptr[node], e1 = rptr[node + 1];
  float a[3] = {0.f, 0.f, 0.f};
  for (int base = e0; base < e1; base += 64) {
    int rem = min(64, e1 - base);
    int c = 0;
    float v = 0.f;
    if (lane < rem) {
      int2 e = sedge[base + lane];
      c = e.x;
      v = __int_as_float(e.y);
    }
    int iters = (rem + 3) >> 2;
#pragma unroll 2
    for (int j = 0; j < iters; j++) {
      int idx = 4 * j + q;               // inactive tail: c=0,v=0 -> adds 0
      int cj = __shfl(c, idx);
      float vj = __shfl(v, idx);
      const float* row = &S2[(size_t)cj * S2_STRIDE + fl * 3];
      a[0] += vj * row[0];
      a[1] += vj * row[1];
      a[2] += vj * row[2];
    }
  }
#pragma unroll
  for (int k = 0; k < 3; k++) {
    a[k] += __shfl_xor(a[k], 16);
    a[k] += __shfl_xor(a[k], 32);
  }
  float x[3];
  float mloc = -INFINITY;
#pragma unroll
  for (int k = 0; k < 3; k++) {
    int f = fl * 3 + k;
    x[k] = (f < N_CLASS) ? (a[k] + b2[f]) : -INFINITY;
    mloc = fmaxf(mloc, x[k]);
  }
#pragma unroll
  for (int o = 1; o < 16; o <<= 1) mloc = fmaxf(mloc, __shfl_xor(mloc, o));
  float sloc = 0.f;
#pragma unroll
  for (int k = 0; k < 3; k++)
    sloc += (fl * 3 + k < N_CLASS) ? expf(x[k] - mloc) : 0.f;
#pragma unroll
  for (int o = 1; o < 16; o <<= 1) sloc += __shfl_xor(sloc, o);
  float ls = logf(sloc);
  if (q == 0) {
#pragma unroll
    for (int k = 0; k < 3; k++) {
      int f = fl * 3 + k;
      if (f < N_CLASS) out[(size_t)node * N_CLASS + f] = (x[k] - mloc) - ls;
    }
  }
}

// ---------------------------------------------------------------------------
extern "C" void kernel_launch(void* const* d_in, const int* in_sizes, int n_in,
                              void* d_out, int out_size, void* d_ws, size_t ws_size,
                              hipStream_t stream) {
  const float* x    = (const float*)d_in[0];
  const float* w1   = (const float*)d_in[1];
  const float* b1   = (const float*)d_in[2];
  const float* w2   = (const float*)d_in[3];
  const float* b2   = (const float*)d_in[4];
  const float* eval = (const float*)d_in[5];
  const int*   erow = (const int*)d_in[6];
  const int*   ecol = (const int*)d_in[7];
  float* out = (float*)d_out;

  char* ws = (char*)d_ws;
  unsigned short* support1 = (unsigned short*)(ws + OFF_SUPPORT1);
  unsigned short* h        = (unsigned short*)(ws + OFF_H);
  float* support2 = (float*)(ws + OFF_SUPPORT2);
  unsigned short* w1t = (unsigned short*)(ws + OFF_W1T);
  int*   rptr   = (int*)(ws + OFF_RPTR);
  int*   bcnt   = (int*)(ws + OFF_BCNT);
  int*   bbase  = (int*)(ws + OFF_BBASE);
  int*   bcur   = (int*)(ws + OFF_BCUR);
  int2*  binned = (int2*)(ws + OFF_BINNED);
  int2*  sedge  = (int2*)(ws + OFF_SEDGE);

  // ---- CSR build (bucketed) + weight prep ----
  hipMemsetAsync(bcnt, 0, N_BUCKETS * 4, stream);
  k_prep_w<<<512, 256, 0, stream>>>(w1, w1t);
  k_bincnt<<<512, 256, 0, stream>>>(erow, bcnt);
  k_binscan<<<1, 256, 0, stream>>>(bcnt, bbase, bcur, rptr);
  k_binscatter<<<N_SC_BLOCKS, 256, 0, stream>>>(erow, ecol, eval, bcur, binned);
  k_bucket_csr<<<N_BUCKETS, 256, 0, stream>>>(binned, bbase, rptr, sedge);

  // ---- layer 1 ----
  k_gemm1<<<dim3((N_NODES + 127) / 128, 1), 256, 0, stream>>>(x, w1t, support1);
  k_spmm1<<<N_NODES / 4, 256, 0, stream>>>(support1, rptr, sedge, b1, h);

  // ---- layer 2 ----
  k_gemm2<<<(N_NODES + 255) / 256, 256, 0, stream>>>(h, w2, support2);
  k_spmm2<<<N_NODES / 4, 256, 0, stream>>>(support2, rptr, sedge, b2, out);
}

// Round 7
// 860.839 us; speedup vs baseline: 1.3713x; 1.0032x over previous
//
#include <hip/hip_runtime.h>
#include <cstdint>
#include <cstddef>

#define N_NODES 100000
#define N_EDGES 3200000
#define IN_FEAT 512
#define HIDDEN  256
#define N_CLASS 40
#define S2_STRIDE 48         // support2 rows padded 40 -> 48 bf16 (96 B)

#define N_BUCKETS 196        // ceil(100000 / 512), bucket = row >> 9
#define SC_CHUNK 4096        // edges per binscatter block (256 thr x 16)
#define N_SC_BLOCKS 782      // ceil(3.2e6 / 4096)

// ---------------------------------------------------------------------------
// Workspace layout (bytes), 256B-aligned
//   support1 : N_NODES*HIDDEN bf16 (row-major) = 51,200,000
//   h        : N_NODES*HIDDEN bf16  =  51,200,000
//   support2 : N_NODES*48 bf16      =   9,600,000
//   w1t      : HIDDEN x IN_FEAT bf16 =    262,144
//   rptr     : (N_NODES+1) i32      ->     400,128
//   bcnt/bbase/bcur : ~196 i32 each ->       1,024 each
//   binned   : N_EDGES int2         =  25,600,000
//   sedge    : N_EDGES int2         =  25,600,000
// total ~164 MB
// ---------------------------------------------------------------------------
#define OFF_SUPPORT1 ((size_t)0)
#define OFF_H        ((size_t)51200000)
#define OFF_SUPPORT2 ((size_t)102400000)
#define OFF_W1T      ((size_t)112000000)
#define OFF_RPTR     ((size_t)112262144)
#define OFF_BCNT     ((size_t)112662272)
#define OFF_BBASE    ((size_t)112663296)
#define OFF_BCUR     ((size_t)112664320)
#define OFF_BINNED   ((size_t)112665344)
#define OFF_SEDGE    ((size_t)138265344)

typedef __attribute__((ext_vector_type(8))) short short8x;
typedef __attribute__((ext_vector_type(4))) float f32x4;
typedef __attribute__((ext_vector_type(8))) unsigned short u16x8;
typedef __attribute__((ext_vector_type(3))) unsigned int u32x3;
typedef __attribute__((ext_vector_type(4))) unsigned int u32x4;

static __device__ __forceinline__ unsigned short f2bf(float f) {
  unsigned u = __float_as_uint(f);
  unsigned r = (u + 0x7FFFu + ((u >> 16) & 1u)) >> 16;  // RNE
  return (unsigned short)r;
}
static __device__ __forceinline__ float bf2f(unsigned short s) {
  return __uint_as_float(((unsigned)s) << 16);
}
static __device__ __forceinline__ float bflo(unsigned u) {
  return __uint_as_float(u << 16);
}
static __device__ __forceinline__ float bfhi(unsigned u) {
  return __uint_as_float(u & 0xFFFF0000u);
}

// --------------- bucket histogram + W1 transpose/cast (merged) --------------
// grid 512 x 256 exactly covers the 131072 w1t elements
__global__ __launch_bounds__(256) void k_bincnt(const int* __restrict__ erow,
                                                int* __restrict__ bcnt,
                                                const float* __restrict__ W,
                                                unsigned short* __restrict__ Wt) {
  int tid = blockIdx.x * 256 + threadIdx.x;
  {
    int n = tid & 255;
    int k = tid >> 8;
    Wt[(size_t)n * IN_FEAT + k] = f2bf(W[(size_t)k * HIDDEN + n]);
  }
  __shared__ int lh[256];
  lh[threadIdx.x] = 0;
  __syncthreads();
  int i = tid;
  int stride = gridDim.x * blockDim.x;
  for (; i < N_EDGES; i += stride) atomicAdd(&lh[erow[i] >> 9], 1);
  __syncthreads();
  if (threadIdx.x < N_BUCKETS) atomicAdd(&bcnt[threadIdx.x], lh[threadIdx.x]);
}

__global__ __launch_bounds__(256) void k_binscan(const int* __restrict__ bcnt,
                                                 int* __restrict__ bbase,
                                                 int* __restrict__ bcur,
                                                 int* __restrict__ rptr) {
  __shared__ int s[256];
  int t = threadIdx.x;
  int v = (t < N_BUCKETS) ? bcnt[t] : 0;
  s[t] = v;
  __syncthreads();
  for (int off = 1; off < 256; off <<= 1) {
    int y = (t >= off) ? s[t - off] : 0;
    __syncthreads();
    s[t] += y;
    __syncthreads();
  }
  if (t < N_BUCKETS) {
    int e = s[t] - v;
    bbase[t] = e;
    bcur[t] = e;
  }
  if (t == 0) {
    bbase[N_BUCKETS] = N_EDGES;
    rptr[N_NODES] = N_EDGES;
  }
}

__global__ __launch_bounds__(256) void k_binscatter(const int* __restrict__ erow,
                                                    const int* __restrict__ ecol,
                                                    const float* __restrict__ eval,
                                                    int* __restrict__ bcur,
                                                    int2* __restrict__ binned) {
  __shared__ int lcnt[256];
  __shared__ int lcur[256];
  const int t = threadIdx.x;
  const int base = blockIdx.x * SC_CHUNK;
  lcnt[t] = 0;
  __syncthreads();
  int rows[16], cols[16], vals[16];
#pragma unroll
  for (int e = 0; e < 16; e++) {
    int i = base + t + e * 256;
    if (i < N_EDGES) {
      rows[e] = erow[i];
      cols[e] = ecol[i];
      vals[e] = __float_as_int(eval[i]);
      atomicAdd(&lcnt[rows[e] >> 9], 1);
    } else {
      rows[e] = -1;
    }
  }
  __syncthreads();
  if (t < N_BUCKETS) lcur[t] = atomicAdd(&bcur[t], lcnt[t]);
  __syncthreads();
#pragma unroll
  for (int e = 0; e < 16; e++) {
    if (rows[e] >= 0) {
      int bkt = rows[e] >> 9;
      int p = atomicAdd(&lcur[bkt], 1);
      binned[p] = make_int2(((rows[e] & 511) << 17) | cols[e], vals[e]);
    }
  }
}

__global__ __launch_bounds__(256) void k_bucket_csr(const int2* __restrict__ binned,
                                                    const int* __restrict__ bbase,
                                                    int* __restrict__ rptr,
                                                    int2* __restrict__ sedge) {
  const int b = blockIdx.x;
  const int t = threadIdx.x;
  __shared__ int cnt[512];
  __shared__ int excl[512];
  __shared__ int s[256];
  cnt[t] = 0;
  cnt[t + 256] = 0;
  __syncthreads();
  const int ebase = bbase[b];
  const int ecnt = bbase[b + 1] - ebase;
  for (int i = t; i < ecnt; i += 256)
    atomicAdd(&cnt[((unsigned)binned[ebase + i].x) >> 17], 1);
  __syncthreads();
  int c0 = cnt[2 * t], c1 = cnt[2 * t + 1];
  s[t] = c0 + c1;
  __syncthreads();
  for (int off = 1; off < 256; off <<= 1) {
    int y = (t >= off) ? s[t - off] : 0;
    __syncthreads();
    s[t] += y;
    __syncthreads();
  }
  int e = s[t] - (c0 + c1);
  excl[2 * t] = e;
  excl[2 * t + 1] = e + c0;
  __syncthreads();
  for (int i = t; i < 512; i += 256) {
    int node = b * 512 + i;
    if (node < N_NODES) rptr[node] = ebase + excl[i];
  }
  __syncthreads();
  for (int i = t; i < ecnt; i += 256) {
    int2 e2 = binned[ebase + i];
    int lrow = ((unsigned)e2.x) >> 17;
    int col = e2.x & 0x1FFFF;
    int p = atomicAdd(&excl[lrow], 1);
    sedge[ebase + p] = make_int2(col, e2.y);
  }
}

// ------------- GEMM1 (MFMA): support1 = bf16(X @ W1), row-major out ---------
// M=100000, N=256 (full width per block -> X read ONCE), K=512.
// 128x256 block tile, 4 waves each 64x128 (4x8 fragments), BK=32.
__global__ __launch_bounds__(256) void k_gemm1(const float* __restrict__ X,
                                               const unsigned short* __restrict__ Wt,
                                               unsigned short* __restrict__ C) {
  __shared__ short As[128 * 32];  // [m][k] 8 KB
  __shared__ short Bs[256 * 32];  // [n][k] 16 KB
  const int t = threadIdx.x;
  const int wave = t >> 6, lane = t & 63;
  const int q = lane >> 4, r = lane & 15;
  const int wm = (wave >> 1) * 64;   // 0 or 64
  const int wn = (wave & 1) * 128;   // 0 or 128
  const int m0 = blockIdx.x * 128;

  f32x4 acc[4][8];
#pragma unroll
  for (int mi = 0; mi < 4; mi++)
#pragma unroll
    for (int ni = 0; ni < 8; ni++) acc[mi][ni] = (f32x4){0.f, 0.f, 0.f, 0.f};

  for (int k0 = 0; k0 < IN_FEAT; k0 += 32) {
    // stage A: 128 rows x 32 k, fp32->bf16 (512 chunks of 8, 2/thread)
#pragma unroll
    for (int i = 0; i < 2; i++) {
      int cidx = t + i * 256;
      int row = cidx >> 2;
      int ko = (cidx & 3) * 8;
      int gr = m0 + row;
      if (gr > N_NODES - 1) gr = N_NODES - 1;
      const float4* src = (const float4*)&X[(size_t)gr * IN_FEAT + k0 + ko];
      float4 x0 = src[0], x1 = src[1];
      short8x a;
      a[0] = (short)f2bf(x0.x); a[1] = (short)f2bf(x0.y);
      a[2] = (short)f2bf(x0.z); a[3] = (short)f2bf(x0.w);
      a[4] = (short)f2bf(x1.x); a[5] = (short)f2bf(x1.y);
      a[6] = (short)f2bf(x1.z); a[7] = (short)f2bf(x1.w);
      *(short8x*)&As[row * 32 + ko] = a;
    }
    // stage B: 256 n-rows x 32 k (1024 chunks of 8, 4/thread)
#pragma unroll
    for (int i = 0; i < 4; i++) {
      int cidx = t + i * 256;
      int row = cidx >> 2;
      int ko = (cidx & 3) * 8;
      short8x b = *(const short8x*)&Wt[(size_t)row * IN_FEAT + k0 + ko];
      *(short8x*)&Bs[row * 32 + ko] = b;
    }
    __syncthreads();
    short8x af[4], bf[8];
#pragma unroll
    for (int mi = 0; mi < 4; mi++)
      af[mi] = *(const short8x*)&As[(wm + mi * 16 + r) * 32 + q * 8];
#pragma unroll
    for (int ni = 0; ni < 8; ni++)
      bf[ni] = *(const short8x*)&Bs[(wn + ni * 16 + r) * 32 + q * 8];
#pragma unroll
    for (int mi = 0; mi < 4; mi++)
#pragma unroll
      for (int ni = 0; ni < 8; ni++)
        acc[mi][ni] = __builtin_amdgcn_mfma_f32_16x16x32_bf16(af[mi], bf[ni],
                                                              acc[mi][ni], 0, 0, 0);
    __syncthreads();
  }
  // epilogue, row-major: C/D layout col=lane&15, row=(lane>>4)*4+reg
#pragma unroll
  for (int mi = 0; mi < 4; mi++) {
#pragma unroll
    for (int ni = 0; ni < 8; ni++) {
      int col = wn + ni * 16 + r;
#pragma unroll
      for (int reg = 0; reg < 4; reg++) {
        int row = m0 + wm + mi * 16 + q * 4 + reg;
        if (row < N_NODES)
          C[(size_t)row * HIDDEN + col] = f2bf(acc[mi][ni][reg]);
      }
    }
  }
}

// ---------------- SpMM1: h = bf16(relu(A @ support1 + b1)) ------------------
// one wave per node; 2 edge-slots x 32 lanes x ushort8 (16 B) per row.
__global__ __launch_bounds__(256) void k_spmm1(const unsigned short* __restrict__ S,
                                               const int* __restrict__ rptr,
                                               const int2* __restrict__ sedge,
                                               const float* __restrict__ b1,
                                               unsigned short* __restrict__ H) {
  const int node = (blockIdx.x * blockDim.x + threadIdx.x) >> 6;
  const int lane = threadIdx.x & 63;
  const int half = lane >> 5;   // edge slot 0/1
  const int fl = lane & 31;     // feature group: feats fl*8 .. fl*8+7
  int e0 = rptr[node], e1 = rptr[node + 1];
  float a[8];
#pragma unroll
  for (int k = 0; k < 8; k++) a[k] = 0.f;
  for (int base = e0; base < e1; base += 64) {
    int rem = min(64, e1 - base);
    int c = 0;
    float v = 0.f;
    if (lane < rem) {
      int2 e = sedge[base + lane];
      c = e.x;
      v = __int_as_float(e.y);
    }
    int iters = (rem + 1) >> 1;
#pragma unroll 8
    for (int j = 0; j < iters; j++) {
      int idx = 2 * j + half;            // inactive tail: c=0,v=0 -> adds 0
      int cj = __shfl(c, idx);
      float vj = __shfl(v, idx);
      short8x s8 = *(const short8x*)&S[(size_t)cj * HIDDEN + fl * 8];
#pragma unroll
      for (int k = 0; k < 8; k++)
        a[k] += vj * bf2f((unsigned short)s8[k]);
    }
  }
#pragma unroll
  for (int k = 0; k < 8; k++) a[k] += __shfl_xor(a[k], 32);
  if (half == 0) {
    float4 b0 = *(const float4*)&b1[fl * 8];
    float4 b4 = *(const float4*)&b1[fl * 8 + 4];
    u16x8 o;
    o[0] = f2bf(fmaxf(a[0] + b0.x, 0.f));
    o[1] = f2bf(fmaxf(a[1] + b0.y, 0.f));
    o[2] = f2bf(fmaxf(a[2] + b0.z, 0.f));
    o[3] = f2bf(fmaxf(a[3] + b0.w, 0.f));
    o[4] = f2bf(fmaxf(a[4] + b4.x, 0.f));
    o[5] = f2bf(fmaxf(a[5] + b4.y, 0.f));
    o[6] = f2bf(fmaxf(a[6] + b4.z, 0.f));
    o[7] = f2bf(fmaxf(a[7] + b4.w, 0.f));
    *(u16x8*)&H[(size_t)node * HIDDEN + fl * 8] = o;
  }
}

// ------- GEMM2: support2 = bf16(H @ W2), rows padded to 48 bf16 (96 B) ------
__global__ __launch_bounds__(256) void k_gemm2(const unsigned short* __restrict__ H,
                                               const float* __restrict__ W2,
                                               unsigned short* __restrict__ S2) {
  __shared__ __align__(16) float Ws[HIDDEN][N_CLASS];  // 40 KB
  __shared__ float Hs[256][33];
  const int t = threadIdx.x;
  const int r0 = blockIdx.x * 256;

#pragma unroll
  for (int i = 0; i < 10; i++) {
    int qq = t + i * 256;
    float4 w = *(const float4*)&W2[(size_t)qq * 4];
    *(float4*)&((float*)Ws)[(size_t)qq * 4] = w;
  }

  float acc[N_CLASS];
#pragma unroll
  for (int n = 0; n < N_CLASS; n++) acc[n] = 0.f;

  for (int kc = 0; kc < HIDDEN; kc += 32) {
    __syncthreads();
#pragma unroll
    for (int i = 0; i < 8; i++) {
      int qq = t + i * 256;
      int row = qq >> 3;
      int kv = (qq & 7) * 4;
      int grow = r0 + row;
      if (grow > N_NODES - 1) grow = N_NODES - 1;
      ushort4 hv = *(const ushort4*)&H[(size_t)grow * HIDDEN + kc + kv];
      Hs[row][kv + 0] = bf2f(hv.x);
      Hs[row][kv + 1] = bf2f(hv.y);
      Hs[row][kv + 2] = bf2f(hv.z);
      Hs[row][kv + 3] = bf2f(hv.w);
    }
    __syncthreads();
    const float4* Wsv = (const float4*)Ws;
#pragma unroll
    for (int k = 0; k < 32; k++) {
      float hk = Hs[t][k];
      int kg = kc + k;
#pragma unroll
      for (int n4 = 0; n4 < 10; n4++) {
        float4 w = Wsv[kg * 10 + n4];
        acc[n4 * 4 + 0] += hk * w.x;
        acc[n4 * 4 + 1] += hk * w.y;
        acc[n4 * 4 + 2] += hk * w.z;
        acc[n4 * 4 + 3] += hk * w.w;
      }
    }
  }
  int row = r0 + t;
  if (row < N_NODES) {
    unsigned pk[24];
#pragma unroll
    for (int i = 0; i < 20; i++)
      pk[i] = (unsigned)f2bf(acc[2 * i]) | ((unsigned)f2bf(acc[2 * i + 1]) << 16);
#pragma unroll
    for (int i = 20; i < 24; i++) pk[i] = 0;  // zero the pad (feats 40..47)
    unsigned* dst = (unsigned*)&S2[(size_t)row * S2_STRIDE];
#pragma unroll
    for (int i = 0; i < 6; i++) {
      u32x4 o = {pk[4 * i], pk[4 * i + 1], pk[4 * i + 2], pk[4 * i + 3]};
      *(u32x4*)&dst[4 * i] = o;
    }
  }
}

// --- SpMM2 + bias + log_softmax: 8 edge-slots x 8 lanes x 6 bf16 (12 B) -----
__global__ __launch_bounds__(256) void k_spmm2(const unsigned short* __restrict__ S2,
                                               const int* __restrict__ rptr,
                                               const int2* __restrict__ sedge,
                                               const float* __restrict__ b2,
                                               float* __restrict__ out) {
  const int node = (blockIdx.x * blockDim.x + threadIdx.x) >> 6;
  const int lane = threadIdx.x & 63;
  const int q = lane >> 3;    // edge slot 0..7
  const int fl = lane & 7;    // feats fl*6 .. fl*6+5 (covers 0..47 incl pad)
  int e0 = rptr[node], e1 = rptr[node + 1];
  float a[6] = {0.f, 0.f, 0.f, 0.f, 0.f, 0.f};
  for (int base = e0; base < e1; base += 64) {
    int rem = min(64, e1 - base);
    int c = 0;
    float v = 0.f;
    if (lane < rem) {
      int2 e = sedge[base + lane];
      c = e.x;
      v = __int_as_float(e.y);
    }
    int iters = (rem + 7) >> 3;
#pragma unroll 4
    for (int j = 0; j < iters; j++) {
      int idx = 8 * j + q;               // inactive tail: c=0,v=0 -> adds 0
      int cj = __shfl(c, idx);
      float vj = __shfl(v, idx);
      u32x3 w = *(const u32x3*)&S2[(size_t)cj * S2_STRIDE + fl * 6];
      a[0] += vj * bflo(w.x);
      a[1] += vj * bfhi(w.x);
      a[2] += vj * bflo(w.y);
      a[3] += vj * bfhi(w.y);
      a[4] += vj * bflo(w.z);
      a[5] += vj * bfhi(w.z);
    }
  }
#pragma unroll
  for (int k = 0; k < 6; k++) {
    a[k] += __shfl_xor(a[k], 8);
    a[k] += __shfl_xor(a[k], 16);
    a[k] += __shfl_xor(a[k], 32);
  }
  float x[6];
  float mloc = -INFINITY;
#pragma unroll
  for (int k = 0; k < 6; k++) {
    int f = fl * 6 + k;
    x[k] = (f < N_CLASS) ? (a[k] + b2[f]) : -INFINITY;
    mloc = fmaxf(mloc, x[k]);
  }
#pragma unroll
  for (int o = 1; o < 8; o <<= 1) mloc = fmaxf(mloc, __shfl_xor(mloc, o));
  float sloc = 0.f;
#pragma unroll
  for (int k = 0; k < 6; k++)
    sloc += (fl * 6 + k < N_CLASS) ? expf(x[k] - mloc) : 0.f;
#pragma unroll
  for (int o = 1; o < 8; o <<= 1) sloc += __shfl_xor(sloc, o);
  float ls = logf(sloc);
  if (q == 0) {
#pragma unroll
    for (int k = 0; k < 6; k++) {
      int f = fl * 6 + k;
      if (f < N_CLASS) out[(size_t)node * N_CLASS + f] = (x[k] - mloc) - ls;
    }
  }
}

// ---------------------------------------------------------------------------
extern "C" void kernel_launch(void* const* d_in, const int* in_sizes, int n_in,
                              void* d_out, int out_size, void* d_ws, size_t ws_size,
                              hipStream_t stream) {
  const float* x    = (const float*)d_in[0];
  const float* w1   = (const float*)d_in[1];
  const float* b1   = (const float*)d_in[2];
  const float* w2   = (const float*)d_in[3];
  const float* b2   = (const float*)d_in[4];
  const float* eval = (const float*)d_in[5];
  const int*   erow = (const int*)d_in[6];
  const int*   ecol = (const int*)d_in[7];
  float* out = (float*)d_out;

  char* ws = (char*)d_ws;
  unsigned short* support1 = (unsigned short*)(ws + OFF_SUPPORT1);
  unsigned short* h        = (unsigned short*)(ws + OFF_H);
  unsigned short* support2 = (unsigned short*)(ws + OFF_SUPPORT2);
  unsigned short* w1t = (unsigned short*)(ws + OFF_W1T);
  int*   rptr   = (int*)(ws + OFF_RPTR);
  int*   bcnt   = (int*)(ws + OFF_BCNT);
  int*   bbase  = (int*)(ws + OFF_BBASE);
  int*   bcur   = (int*)(ws + OFF_BCUR);
  int2*  binned = (int2*)(ws + OFF_BINNED);
  int2*  sedge  = (int2*)(ws + OFF_SEDGE);

  // ---- CSR build (bucketed) + weight prep ----
  hipMemsetAsync(bcnt, 0, N_BUCKETS * 4, stream);
  k_bincnt<<<512, 256, 0, stream>>>(erow, bcnt, w1, w1t);
  k_binscan<<<1, 256, 0, stream>>>(bcnt, bbase, bcur, rptr);
  k_binscatter<<<N_SC_BLOCKS, 256, 0, stream>>>(erow, ecol, eval, bcur, binned);
  k_bucket_csr<<<N_BUCKETS, 256, 0, stream>>>(binned, bbase, rptr, sedge);

  // ---- layer 1 ----
  k_gemm1<<<dim3((N_NODES + 127) / 128, 1), 256, 0, stream>>>(x, w1t, support1);
  k_spmm1<<<N_NODES / 4, 256, 0, stream>>>(support1, rptr, sedge, b1, h);

  // ---- layer 2 ----
  k_gemm2<<<(N_NODES + 255) / 256, 256, 0, stream>>>(h, w2, support2);
  k_spmm2<<<N_NODES / 4, 256, 0, stream>>>(support2, rptr, sedge, b2, out);
}

// Round 8
// 803.313 us; speedup vs baseline: 1.4695x; 1.0716x over previous
//
#include <hip/hip_runtime.h>
#include <cstdint>
#include <cstddef>

#define N_NODES 100000
#define N_EDGES 3200000
#define IN_FEAT 512
#define HIDDEN  256
#define N_CLASS 40
#define S2_STRIDE 48         // support2 rows padded 40 -> 48 bf16 (96 B)

#define N_BUCKETS 196        // ceil(100000 / 512), bucket = row >> 9
#define SC_CHUNK 4096        // edges per binscatter block (256 thr x 16)
#define N_SC_BLOCKS 782      // ceil(3.2e6 / 4096)

// ---------------------------------------------------------------------------
// Workspace layout (bytes), 256B-aligned
//   support1 : N_NODES*HIDDEN bf16 (row-major) = 51,200,000
//   h        : N_NODES*HIDDEN bf16  =  51,200,000
//   support2 : N_NODES*48 bf16      =   9,600,000
//   w1t      : HIDDEN x IN_FEAT bf16 =    262,144
//   w2t      : 48 x HIDDEN bf16      =     24,576 -> 24,832 pad
//   rptr     : (N_NODES+1) i32      ->     400,128
//   bcnt/bbase/bcur : ~196 i32 each ->       1,024 each
//   binned   : N_EDGES int2         =  25,600,000
//   sedge    : N_EDGES int2         =  25,600,000
// ---------------------------------------------------------------------------
#define OFF_SUPPORT1 ((size_t)0)
#define OFF_H        ((size_t)51200000)
#define OFF_SUPPORT2 ((size_t)102400000)
#define OFF_W1T      ((size_t)112000000)
#define OFF_W2T      ((size_t)112262144)
#define OFF_RPTR     ((size_t)112286976)
#define OFF_BCNT     ((size_t)112687104)
#define OFF_BBASE    ((size_t)112688128)
#define OFF_BCUR     ((size_t)112689152)
#define OFF_BINNED   ((size_t)112690176)
#define OFF_SEDGE    ((size_t)138290176)

typedef __attribute__((ext_vector_type(8))) short short8x;
typedef __attribute__((ext_vector_type(4))) float f32x4;
typedef __attribute__((ext_vector_type(8))) unsigned short u16x8;
typedef __attribute__((ext_vector_type(3))) unsigned int u32x3;
typedef __attribute__((ext_vector_type(4))) unsigned int u32x4;

static __device__ __forceinline__ unsigned short f2bf(float f) {
  unsigned u = __float_as_uint(f);
  unsigned r = (u + 0x7FFFu + ((u >> 16) & 1u)) >> 16;  // RNE
  return (unsigned short)r;
}
static __device__ __forceinline__ float bf2f(unsigned short s) {
  return __uint_as_float(((unsigned)s) << 16);
}
static __device__ __forceinline__ float bflo(unsigned u) {
  return __uint_as_float(u << 16);
}
static __device__ __forceinline__ float bfhi(unsigned u) {
  return __uint_as_float(u & 0xFFFF0000u);
}

// ------- bucket histogram + W1/W2 transpose/cast (merged, spare threads) ----
// grid 512 x 256 = 131072 threads: covers w1t (131072 elems) and w2t (12288)
__global__ __launch_bounds__(256) void k_bincnt(const int* __restrict__ erow,
                                                int* __restrict__ bcnt,
                                                const float* __restrict__ W1,
                                                unsigned short* __restrict__ W1t,
                                                const float* __restrict__ W2,
                                                unsigned short* __restrict__ W2t) {
  int tid = blockIdx.x * 256 + threadIdx.x;
  {
    int n = tid & 255;
    int k = tid >> 8;
    W1t[(size_t)n * IN_FEAT + k] = f2bf(W1[(size_t)k * HIDDEN + n]);
  }
  if (tid < 48 * HIDDEN) {
    int n = tid >> 8;          // 0..47
    int k = tid & 255;         // 0..255
    W2t[n * HIDDEN + k] = (n < N_CLASS) ? f2bf(W2[(size_t)k * N_CLASS + n]) : 0;
  }
  __shared__ int lh[256];
  lh[threadIdx.x] = 0;
  __syncthreads();
  int i = tid;
  int stride = gridDim.x * blockDim.x;
  for (; i < N_EDGES; i += stride) atomicAdd(&lh[erow[i] >> 9], 1);
  __syncthreads();
  if (threadIdx.x < N_BUCKETS) atomicAdd(&bcnt[threadIdx.x], lh[threadIdx.x]);
}

__global__ __launch_bounds__(256) void k_binscan(const int* __restrict__ bcnt,
                                                 int* __restrict__ bbase,
                                                 int* __restrict__ bcur,
                                                 int* __restrict__ rptr) {
  __shared__ int s[256];
  int t = threadIdx.x;
  int v = (t < N_BUCKETS) ? bcnt[t] : 0;
  s[t] = v;
  __syncthreads();
  for (int off = 1; off < 256; off <<= 1) {
    int y = (t >= off) ? s[t - off] : 0;
    __syncthreads();
    s[t] += y;
    __syncthreads();
  }
  if (t < N_BUCKETS) {
    int e = s[t] - v;
    bbase[t] = e;
    bcur[t] = e;
  }
  if (t == 0) {
    bbase[N_BUCKETS] = N_EDGES;
    rptr[N_NODES] = N_EDGES;
  }
}

__global__ __launch_bounds__(256) void k_binscatter(const int* __restrict__ erow,
                                                    const int* __restrict__ ecol,
                                                    const float* __restrict__ eval,
                                                    int* __restrict__ bcur,
                                                    int2* __restrict__ binned) {
  __shared__ int lcnt[256];
  __shared__ int lcur[256];
  const int t = threadIdx.x;
  const int base = blockIdx.x * SC_CHUNK;
  lcnt[t] = 0;
  __syncthreads();
  int rows[16], cols[16], vals[16];
#pragma unroll
  for (int e = 0; e < 16; e++) {
    int i = base + t + e * 256;
    if (i < N_EDGES) {
      rows[e] = erow[i];
      cols[e] = ecol[i];
      vals[e] = __float_as_int(eval[i]);
      atomicAdd(&lcnt[rows[e] >> 9], 1);
    } else {
      rows[e] = -1;
    }
  }
  __syncthreads();
  if (t < N_BUCKETS) lcur[t] = atomicAdd(&bcur[t], lcnt[t]);
  __syncthreads();
#pragma unroll
  for (int e = 0; e < 16; e++) {
    if (rows[e] >= 0) {
      int bkt = rows[e] >> 9;
      int p = atomicAdd(&lcur[bkt], 1);
      binned[p] = make_int2(((rows[e] & 511) << 17) | cols[e], vals[e]);
    }
  }
}

__global__ __launch_bounds__(256) void k_bucket_csr(const int2* __restrict__ binned,
                                                    const int* __restrict__ bbase,
                                                    int* __restrict__ rptr,
                                                    int2* __restrict__ sedge) {
  const int b = blockIdx.x;
  const int t = threadIdx.x;
  __shared__ int cnt[512];
  __shared__ int excl[512];
  __shared__ int s[256];
  cnt[t] = 0;
  cnt[t + 256] = 0;
  __syncthreads();
  const int ebase = bbase[b];
  const int ecnt = bbase[b + 1] - ebase;
  for (int i = t; i < ecnt; i += 256)
    atomicAdd(&cnt[((unsigned)binned[ebase + i].x) >> 17], 1);
  __syncthreads();
  int c0 = cnt[2 * t], c1 = cnt[2 * t + 1];
  s[t] = c0 + c1;
  __syncthreads();
  for (int off = 1; off < 256; off <<= 1) {
    int y = (t >= off) ? s[t - off] : 0;
    __syncthreads();
    s[t] += y;
    __syncthreads();
  }
  int e = s[t] - (c0 + c1);
  excl[2 * t] = e;
  excl[2 * t + 1] = e + c0;
  __syncthreads();
  for (int i = t; i < 512; i += 256) {
    int node = b * 512 + i;
    if (node < N_NODES) rptr[node] = ebase + excl[i];
  }
  __syncthreads();
  for (int i = t; i < ecnt; i += 256) {
    int2 e2 = binned[ebase + i];
    int lrow = ((unsigned)e2.x) >> 17;
    int col = e2.x & 0x1FFFF;
    int p = atomicAdd(&excl[lrow], 1);
    sedge[ebase + p] = make_int2(col, e2.y);
  }
}

// ------------- GEMM1 (MFMA): support1 = bf16(X @ W1), row-major out ---------
// M=100000, N=256 (full width per block -> X read ONCE), K=512.
// 128x256 block tile, 4 waves each 64x128 (4x8 fragments), BK=32.
__global__ __launch_bounds__(256) void k_gemm1(const float* __restrict__ X,
                                               const unsigned short* __restrict__ Wt,
                                               unsigned short* __restrict__ C) {
  __shared__ short As[128 * 32];  // [m][k] 8 KB
  __shared__ short Bs[256 * 32];  // [n][k] 16 KB
  const int t = threadIdx.x;
  const int wave = t >> 6, lane = t & 63;
  const int q = lane >> 4, r = lane & 15;
  const int wm = (wave >> 1) * 64;   // 0 or 64
  const int wn = (wave & 1) * 128;   // 0 or 128
  const int m0 = blockIdx.x * 128;

  f32x4 acc[4][8];
#pragma unroll
  for (int mi = 0; mi < 4; mi++)
#pragma unroll
    for (int ni = 0; ni < 8; ni++) acc[mi][ni] = (f32x4){0.f, 0.f, 0.f, 0.f};

  for (int k0 = 0; k0 < IN_FEAT; k0 += 32) {
#pragma unroll
    for (int i = 0; i < 2; i++) {
      int cidx = t + i * 256;
      int row = cidx >> 2;
      int ko = (cidx & 3) * 8;
      int gr = m0 + row;
      if (gr > N_NODES - 1) gr = N_NODES - 1;
      const float4* src = (const float4*)&X[(size_t)gr * IN_FEAT + k0 + ko];
      float4 x0 = src[0], x1 = src[1];
      short8x a;
      a[0] = (short)f2bf(x0.x); a[1] = (short)f2bf(x0.y);
      a[2] = (short)f2bf(x0.z); a[3] = (short)f2bf(x0.w);
      a[4] = (short)f2bf(x1.x); a[5] = (short)f2bf(x1.y);
      a[6] = (short)f2bf(x1.z); a[7] = (short)f2bf(x1.w);
      *(short8x*)&As[row * 32 + ko] = a;
    }
#pragma unroll
    for (int i = 0; i < 4; i++) {
      int cidx = t + i * 256;
      int row = cidx >> 2;
      int ko = (cidx & 3) * 8;
      short8x b = *(const short8x*)&Wt[(size_t)row * IN_FEAT + k0 + ko];
      *(short8x*)&Bs[row * 32 + ko] = b;
    }
    __syncthreads();
    short8x af[4], bf[8];
#pragma unroll
    for (int mi = 0; mi < 4; mi++)
      af[mi] = *(const short8x*)&As[(wm + mi * 16 + r) * 32 + q * 8];
#pragma unroll
    for (int ni = 0; ni < 8; ni++)
      bf[ni] = *(const short8x*)&Bs[(wn + ni * 16 + r) * 32 + q * 8];
#pragma unroll
    for (int mi = 0; mi < 4; mi++)
#pragma unroll
      for (int ni = 0; ni < 8; ni++)
        acc[mi][ni] = __builtin_amdgcn_mfma_f32_16x16x32_bf16(af[mi], bf[ni],
                                                              acc[mi][ni], 0, 0, 0);
    __syncthreads();
  }
#pragma unroll
  for (int mi = 0; mi < 4; mi++) {
#pragma unroll
    for (int ni = 0; ni < 8; ni++) {
      int col = wn + ni * 16 + r;
#pragma unroll
      for (int reg = 0; reg < 4; reg++) {
        int row = m0 + wm + mi * 16 + q * 4 + reg;
        if (row < N_NODES)
          C[(size_t)row * HIDDEN + col] = f2bf(acc[mi][ni][reg]);
      }
    }
  }
}

// ---------------- SpMM1: h = bf16(relu(A @ support1 + b1)) ------------------
// one wave per node; 2 edge-slots x 32 lanes x ushort8 (16 B) per row.
// launched as TWO half-grids (diagnostic: expose other kernels in top-5)
__global__ __launch_bounds__(256) void k_spmm1(const unsigned short* __restrict__ S,
                                               const int* __restrict__ rptr,
                                               const int2* __restrict__ sedge,
                                               const float* __restrict__ b1,
                                               unsigned short* __restrict__ H,
                                               int node_off) {
  const int node = node_off + ((blockIdx.x * blockDim.x + threadIdx.x) >> 6);
  const int lane = threadIdx.x & 63;
  const int half = lane >> 5;   // edge slot 0/1
  const int fl = lane & 31;     // feature group: feats fl*8 .. fl*8+7
  int e0 = rptr[node], e1 = rptr[node + 1];
  float a[8];
#pragma unroll
  for (int k = 0; k < 8; k++) a[k] = 0.f;
  for (int base = e0; base < e1; base += 64) {
    int rem = min(64, e1 - base);
    int c = 0;
    float v = 0.f;
    if (lane < rem) {
      int2 e = sedge[base + lane];
      c = e.x;
      v = __int_as_float(e.y);
    }
    int iters = (rem + 1) >> 1;
#pragma unroll 8
    for (int j = 0; j < iters; j++) {
      int idx = 2 * j + half;            // inactive tail: c=0,v=0 -> adds 0
      int cj = __shfl(c, idx);
      float vj = __shfl(v, idx);
      short8x s8 = *(const short8x*)&S[(size_t)cj * HIDDEN + fl * 8];
#pragma unroll
      for (int k = 0; k < 8; k++)
        a[k] += vj * bf2f((unsigned short)s8[k]);
    }
  }
#pragma unroll
  for (int k = 0; k < 8; k++) a[k] += __shfl_xor(a[k], 32);
  if (half == 0) {
    float4 b0 = *(const float4*)&b1[fl * 8];
    float4 b4 = *(const float4*)&b1[fl * 8 + 4];
    u16x8 o;
    o[0] = f2bf(fmaxf(a[0] + b0.x, 0.f));
    o[1] = f2bf(fmaxf(a[1] + b0.y, 0.f));
    o[2] = f2bf(fmaxf(a[2] + b0.z, 0.f));
    o[3] = f2bf(fmaxf(a[3] + b0.w, 0.f));
    o[4] = f2bf(fmaxf(a[4] + b4.x, 0.f));
    o[5] = f2bf(fmaxf(a[5] + b4.y, 0.f));
    o[6] = f2bf(fmaxf(a[6] + b4.z, 0.f));
    o[7] = f2bf(fmaxf(a[7] + b4.w, 0.f));
    *(u16x8*)&H[(size_t)node * HIDDEN + fl * 8] = o;
  }
}

// ------- GEMM2 (MFMA): support2 = bf16(H @ W2t^T), 48-col, K=256 ------------
// grid = ceil(100000/64), block 256 = 4 waves; wave = 16 rows x 48 cols.
// A,B frags loaded straight from global (H bf16, W2t bf16 L2-resident).
__global__ __launch_bounds__(256) void k_gemm2(const unsigned short* __restrict__ H,
                                               const unsigned short* __restrict__ W2t,
                                               unsigned short* __restrict__ S2) {
  const int t = threadIdx.x;
  const int wave = t >> 6, lane = t & 63;
  const int q = lane >> 4, r = lane & 15;
  const int m0 = blockIdx.x * 64 + wave * 16;

  f32x4 acc[3];
#pragma unroll
  for (int n = 0; n < 3; n++) acc[n] = (f32x4){0.f, 0.f, 0.f, 0.f};

  int arow = m0 + r;
  if (arow > N_NODES - 1) arow = N_NODES - 1;
  const unsigned short* Arow = &H[(size_t)arow * HIDDEN + q * 8];

#pragma unroll
  for (int k0 = 0; k0 < HIDDEN; k0 += 32) {
    short8x af = *(const short8x*)&Arow[k0];
    short8x bf0 = *(const short8x*)&W2t[(0 * 16 + r) * HIDDEN + k0 + q * 8];
    short8x bf1 = *(const short8x*)&W2t[(1 * 16 + r) * HIDDEN + k0 + q * 8];
    short8x bf2 = *(const short8x*)&W2t[(2 * 16 + r) * HIDDEN + k0 + q * 8];
    acc[0] = __builtin_amdgcn_mfma_f32_16x16x32_bf16(af, bf0, acc[0], 0, 0, 0);
    acc[1] = __builtin_amdgcn_mfma_f32_16x16x32_bf16(af, bf1, acc[1], 0, 0, 0);
    acc[2] = __builtin_amdgcn_mfma_f32_16x16x32_bf16(af, bf2, acc[2], 0, 0, 0);
  }
  // C layout: col = r, row = q*4+reg
#pragma unroll
  for (int n = 0; n < 3; n++) {
#pragma unroll
    for (int reg = 0; reg < 4; reg++) {
      int row = m0 + q * 4 + reg;
      if (row < N_NODES)
        S2[(size_t)row * S2_STRIDE + n * 16 + r] = f2bf(acc[n][reg]);
    }
  }
}

// --- SpMM2 + bias + log_softmax: 8 edge-slots x 8 lanes x 6 bf16 (12 B) -----
__global__ __launch_bounds__(256) void k_spmm2(const unsigned short* __restrict__ S2,
                                               const int* __restrict__ rptr,
                                               const int2* __restrict__ sedge,
                                               const float* __restrict__ b2,
                                               float* __restrict__ out) {
  const int node = (blockIdx.x * blockDim.x + threadIdx.x) >> 6;
  const int lane = threadIdx.x & 63;
  const int q = lane >> 3;    // edge slot 0..7
  const int fl = lane & 7;    // feats fl*6 .. fl*6+5 (covers 0..47 incl pad)
  int e0 = rptr[node], e1 = rptr[node + 1];
  float a[6] = {0.f, 0.f, 0.f, 0.f, 0.f, 0.f};
  for (int base = e0; base < e1; base += 64) {
    int rem = min(64, e1 - base);
    int c = 0;
    float v = 0.f;
    if (lane < rem) {
      int2 e = sedge[base + lane];
      c = e.x;
      v = __int_as_float(e.y);
    }
    int iters = (rem + 7) >> 3;
#pragma unroll 8
    for (int j = 0; j < iters; j++) {
      int idx = 8 * j + q;               // inactive tail: c=0,v=0 -> adds 0
      int cj = __shfl(c, idx);
      float vj = __shfl(v, idx);
      u32x3 w = *(const u32x3*)&S2[(size_t)cj * S2_STRIDE + fl * 6];
      a[0] += vj * bflo(w.x);
      a[1] += vj * bfhi(w.x);
      a[2] += vj * bflo(w.y);
      a[3] += vj * bfhi(w.y);
      a[4] += vj * bflo(w.z);
      a[5] += vj * bfhi(w.z);
    }
  }
#pragma unroll
  for (int k = 0; k < 6; k++) {
    a[k] += __shfl_xor(a[k], 8);
    a[k] += __shfl_xor(a[k], 16);
    a[k] += __shfl_xor(a[k], 32);
  }
  float x[6];
  float mloc = -INFINITY;
#pragma unroll
  for (int k = 0; k < 6; k++) {
    int f = fl * 6 + k;
    x[k] = (f < N_CLASS) ? (a[k] + b2[f]) : -INFINITY;
    mloc = fmaxf(mloc, x[k]);
  }
#pragma unroll
  for (int o = 1; o < 8; o <<= 1) mloc = fmaxf(mloc, __shfl_xor(mloc, o));
  float sloc = 0.f;
#pragma unroll
  for (int k = 0; k < 6; k++)
    sloc += (fl * 6 + k < N_CLASS) ? expf(x[k] - mloc) : 0.f;
#pragma unroll
  for (int o = 1; o < 8; o <<= 1) sloc += __shfl_xor(sloc, o);
  float ls = logf(sloc);
  if (q == 0) {
#pragma unroll
    for (int k = 0; k < 6; k++) {
      int f = fl * 6 + k;
      if (f < N_CLASS) out[(size_t)node * N_CLASS + f] = (x[k] - mloc) - ls;
    }
  }
}

// ---------------------------------------------------------------------------
extern "C" void kernel_launch(void* const* d_in, const int* in_sizes, int n_in,
                              void* d_out, int out_size, void* d_ws, size_t ws_size,
                              hipStream_t stream) {
  const float* x    = (const float*)d_in[0];
  const float* w1   = (const float*)d_in[1];
  const float* b1   = (const float*)d_in[2];
  const float* w2   = (const float*)d_in[3];
  const float* b2   = (const float*)d_in[4];
  const float* eval = (const float*)d_in[5];
  const int*   erow = (const int*)d_in[6];
  const int*   ecol = (const int*)d_in[7];
  float* out = (float*)d_out;

  char* ws = (char*)d_ws;
  unsigned short* support1 = (unsigned short*)(ws + OFF_SUPPORT1);
  unsigned short* h        = (unsigned short*)(ws + OFF_H);
  unsigned short* support2 = (unsigned short*)(ws + OFF_SUPPORT2);
  unsigned short* w1t = (unsigned short*)(ws + OFF_W1T);
  unsigned short* w2t = (unsigned short*)(ws + OFF_W2T);
  int*   rptr   = (int*)(ws + OFF_RPTR);
  int*   bcnt   = (int*)(ws + OFF_BCNT);
  int*   bbase  = (int*)(ws + OFF_BBASE);
  int*   bcur   = (int*)(ws + OFF_BCUR);
  int2*  binned = (int2*)(ws + OFF_BINNED);
  int2*  sedge  = (int2*)(ws + OFF_SEDGE);

  // ---- CSR build (bucketed) + weight prep ----
  hipMemsetAsync(bcnt, 0, N_BUCKETS * 4, stream);
  k_bincnt<<<512, 256, 0, stream>>>(erow, bcnt, w1, w1t, w2, w2t);
  k_binscan<<<1, 256, 0, stream>>>(bcnt, bbase, bcur, rptr);
  k_binscatter<<<N_SC_BLOCKS, 256, 0, stream>>>(erow, ecol, eval, bcur, binned);
  k_bucket_csr<<<N_BUCKETS, 256, 0, stream>>>(binned, bbase, rptr, sedge);

  // ---- layer 1 ----
  k_gemm1<<<dim3((N_NODES + 127) / 128, 1), 256, 0, stream>>>(x, w1t, support1);
  k_spmm1<<<N_NODES / 8, 256, 0, stream>>>(support1, rptr, sedge, b1, h, 0);
  k_spmm1<<<N_NODES / 8, 256, 0, stream>>>(support1, rptr, sedge, b1, h, N_NODES / 2);

  // ---- layer 2 ----
  k_gemm2<<<(N_NODES + 63) / 64, 256, 0, stream>>>(h, w2t, support2);
  k_spmm2<<<N_NODES / 4, 256, 0, stream>>>(support2, rptr, sedge, b2, out);
}